// Round 11
// baseline (280.163 us; speedup 1.0000x reference)
//
#include <hip/hip_runtime.h>
#include <hip/hip_bf16.h>
#include <stdint.h>
#include <stddef.h>

#define EMB 768
#define FFD 3072
#define NHEAD 12
#define HD 64
#define SEQ 1024
#define NTOK 8192
#define QKVW 2304

typedef unsigned short u16;
typedef __attribute__((ext_vector_type(8))) short short8;
typedef __attribute__((ext_vector_type(4))) float f32x4;

__device__ __forceinline__ u16 f2bf(float f) {
  union { float f; uint32_t u; } w; w.f = f;
  uint32_t x = w.u + 0x7fffu + ((w.u >> 16) & 1u);
  return (u16)(x >> 16);
}

__device__ __forceinline__ float bf2f(uint32_t v) {
  union { uint32_t u; float f; } c; c.u = v << 16; return c.f;
}

__device__ __forceinline__ uint32_t pkbf(float lo, float hi) {
  __hip_bfloat162 h = __float22bfloat162_rn(float2{lo, hi});
  union { __hip_bfloat162 h; uint32_t u; } cv; cv.h = h;
  return cv.u;
}

__device__ __forceinline__ void g2l16(const void* g, void* l) {
  __builtin_amdgcn_global_load_lds(
      (const __attribute__((address_space(1))) void*)g,
      (__attribute__((address_space(3))) void*)l, 16, 0, 0);
}

// ------------- prep kernel: 6 weight transposes + LN1, flat block decode ------
// [0,1728) Wq/Wk/Wv  [1728,2304) Wo  [2304,4608) W1  [4608,6912) W2
// [6912,8960) LN1 over x (4 rows/block, wave-per-row)
__global__ __launch_bounds__(256)
void prep_kernel(const float* __restrict__ Wq, const float* __restrict__ Wk,
                 const float* __restrict__ Wv, const float* __restrict__ Wo,
                 const float* __restrict__ W1, const float* __restrict__ W2,
                 u16* __restrict__ qkvT, u16* __restrict__ woT,
                 u16* __restrict__ w1T, u16* __restrict__ w2T,
                 const float* __restrict__ x, const float* __restrict__ sc,
                 const float* __restrict__ sh, u16* __restrict__ h1) {
  __shared__ float tile[32][33];
  const int id = blockIdx.x;
  if (id >= 6912) {
    // LN1 path
    const int wave = threadIdx.x >> 6, lane = threadIdx.x & 63;
    const int row = (id - 6912) * 4 + wave;
    const float* xr = x + (size_t)row * EMB;
    float4 v[3];
    float s = 0.f, ss = 0.f;
#pragma unroll
    for (int i = 0; i < 3; ++i) {
      v[i] = *(const float4*)(xr + lane * 4 + i * 256);
      s += v[i].x + v[i].y + v[i].z + v[i].w;
      ss += v[i].x * v[i].x + v[i].y * v[i].y + v[i].z * v[i].z + v[i].w * v[i].w;
    }
#pragma unroll
    for (int m = 1; m < 64; m <<= 1) { s += __shfl_xor(s, m, 64); ss += __shfl_xor(ss, m, 64); }
    const float mean = s * (1.f / EMB);
    const float inv = rsqrtf(ss * (1.f / EMB) - mean * mean + 1e-5f);
    u16* orow = h1 + (size_t)row * EMB;
#pragma unroll
    for (int i = 0; i < 3; ++i) {
      const int c = lane * 4 + i * 256;
      const float4 s4 = *(const float4*)(sc + c);
      const float4 h4 = *(const float4*)(sh + c);
      uint2 w2;
      w2.x = pkbf((v[i].x - mean) * inv * s4.x + h4.x, (v[i].y - mean) * inv * s4.y + h4.y);
      w2.y = pkbf((v[i].z - mean) * inv * s4.z + h4.z, (v[i].w - mean) * inv * s4.w + h4.w);
      *(uint2*)(orow + c) = w2;
    }
    return;
  }
  const float* in; u16* out; int K, N, bx, by;
  if (id < 1728) {
    const int z = id / 576, rem = id % 576;
    in = z == 0 ? Wq : (z == 1 ? Wk : Wv);
    out = qkvT + (size_t)z * EMB * EMB;
    K = EMB; N = EMB; bx = rem % 24; by = rem / 24;
  } else if (id < 2304) {
    const int rem = id - 1728;
    in = Wo; out = woT; K = EMB; N = EMB; bx = rem % 24; by = rem / 24;
  } else if (id < 4608) {
    const int rem = id - 2304;
    in = W1; out = w1T; K = EMB; N = FFD; bx = rem % 96; by = rem / 96;
  } else {
    const int rem = id - 4608;
    in = W2; out = w2T; K = FFD; N = EMB; bx = rem % 24; by = rem / 24;
  }
  const int n0 = bx * 32, k0 = by * 32;
  const int tx = threadIdx.x & 31;
  const int ty = threadIdx.x >> 5;
#pragma unroll
  for (int i = 0; i < 32; i += 8)
    tile[ty + i][tx] = in[(size_t)(k0 + ty + i) * N + n0 + tx];
  __syncthreads();
#pragma unroll
  for (int i = 0; i < 32; i += 8)
    out[(size_t)(n0 + ty + i) * K + k0 + tx] = f2bf(tile[tx][ty + i]);
}

// layernorm, wave-per-row, vectorized (bf16 in)
__global__ __launch_bounds__(256)
void ln_bf_vec_kernel(const u16* __restrict__ x, const float* __restrict__ sc,
                      const float* __restrict__ sh, u16* __restrict__ out) {
  const int wave = threadIdx.x >> 6, lane = threadIdx.x & 63;
  const int row = blockIdx.x * 4 + wave;
  const u16* xr = x + (size_t)row * EMB;
  float v[3][4];
  float s = 0.f, ss = 0.f;
#pragma unroll
  for (int i = 0; i < 3; ++i) {
    const uint2 r2 = *(const uint2*)(xr + lane * 4 + i * 256);
    v[i][0] = bf2f(r2.x & 0xffffu);
    v[i][1] = bf2f(r2.x >> 16);
    v[i][2] = bf2f(r2.y & 0xffffu);
    v[i][3] = bf2f(r2.y >> 16);
#pragma unroll
    for (int j = 0; j < 4; ++j) { s += v[i][j]; ss += v[i][j] * v[i][j]; }
  }
#pragma unroll
  for (int m = 1; m < 64; m <<= 1) { s += __shfl_xor(s, m, 64); ss += __shfl_xor(ss, m, 64); }
  const float mean = s * (1.f / EMB);
  const float inv = rsqrtf(ss * (1.f / EMB) - mean * mean + 1e-5f);
  u16* orow = out + (size_t)row * EMB;
#pragma unroll
  for (int i = 0; i < 3; ++i) {
    const int c = lane * 4 + i * 256;
    const float4 s4 = *(const float4*)(sc + c);
    const float4 h4 = *(const float4*)(sh + c);
    uint2 w2;
    w2.x = pkbf((v[i][0] - mean) * inv * s4.x + h4.x, (v[i][1] - mean) * inv * s4.y + h4.y);
    w2.y = pkbf((v[i][2] - mean) * inv * s4.z + h4.z, (v[i][3] - mean) * inv * s4.w + h4.w);
    *(uint2*)(orow + c) = w2;
  }
}

// ---------------- bf16 GEMM: C[M,N] = A[M,K] @ BT[N,K]^T ----------------
// BK=32 DOUBLE-BUFFERED at same LDS footprint as r7 single-buffer (32KB@MT=128).
// Loop: barrier -> stage(t+1 -> buf^1) -> ds_read+MFMA(buf).  1 barrier/tile;
// load latency hides under the compute phase; totals (MFMA/ds_read/g2l/barriers)
// identical to r7 - only overlap structure differs.  Swizzle for 32-elem rows:
// e ^= (row&3)<<3 (8x16B-group spread, same multiplicity as verified BK=64).
// SWAP=true: mfma(bf, af) -> lane holds one M-row, 4 consecutive N-cols.
// EPI 2 (SWAP): C bf16 = gelu_tanh(acc + bias[n])          (uint2 st)
// EPI 4 (SWAP): C bf16 = acc + bias[n] + resf32[m*N+n]     (uint2 st)
// EPI 5 (SWAP): C f32  = acc + bias[n] + bf2f(res16[...])  (float4 st)
// EPI 3 (!SWAP): QKV split (cols<1536 row-major bf16; V cols -> vTp transposed)
template <int EPI, int MT, bool SWAP>
__global__ __launch_bounds__(256)
void gemm_kernel(const u16* __restrict__ A, const u16* __restrict__ BT,
                 void* __restrict__ Cp, const float* __restrict__ bias,
                 const float* __restrict__ res, const u16* __restrict__ res16,
                 u16* __restrict__ vTp, int M, int N, int K) {
  constexpr int MI = MT / 32;
  __shared__ u16 As[2][MT * 32];
  __shared__ u16 Bs[2][128 * 32];

  const int nwg = gridDim.x * gridDim.y;
  const int orig = blockIdx.y * gridDim.x + blockIdx.x;
  const int swz = (orig & 7) * (nwg >> 3) + (orig >> 3);
  const int m0 = (swz / gridDim.x) * MT;
  const int n0 = (swz % gridDim.x) * 128;

  const int tid = threadIdx.x;
  const int wave = tid >> 6, lane = tid & 63;
  const int wr = wave >> 1, wc = wave & 1;
  const int r = lane & 15, g = lane >> 4;
  const int strow = wave * 16 + (lane >> 2);      // staging row 0..63 per round
  const int e0 = ((lane & 3) * 8) ^ ((strow & 3) << 3);  // pre-swizzled src col

  f32x4 acc[MI][4] = {};

  // stage K-tile kt into dbuf buf: per wave, linear LDS dest (uniform base),
  // per-lane swizzled global source (rule #21)
  auto stage = [&](int buf, int kt) {
    const int k0 = kt << 5;
#pragma unroll
    for (int ra = 0; ra < MT / 64; ++ra)
      g2l16(A + (size_t)(m0 + ra * 64 + strow) * K + k0 + e0,
            (u16*)As[buf] + ra * 2048 + wave * 512);
#pragma unroll
    for (int rb = 0; rb < 2; ++rb)
      g2l16(BT + (size_t)(n0 + rb * 64 + strow) * K + k0 + e0,
            (u16*)Bs[buf] + rb * 2048 + wave * 512);
  };

  const int nkt = K >> 5;
  stage(0, 0);
  for (int kt = 0; kt < nkt; ++kt) {
    __syncthreads();  // drains stage(kt) (issued one compute-phase ago)
    const int cur = kt & 1;
    if (kt + 1 < nkt) stage(cur ^ 1, kt + 1);
    const u16* ab = (const u16*)As[cur];
    const u16* bb = (const u16*)Bs[cur];
    short8 af[MI], bf[4];
#pragma unroll
    for (int mi = 0; mi < MI; ++mi) {
      const int row = wr * (MT / 2) + mi * 16 + r;
      af[mi] = *(const short8*)(ab + row * 32 + ((g * 8) ^ ((row & 3) << 3)));
    }
#pragma unroll
    for (int ni = 0; ni < 4; ++ni) {
      const int row = wc * 64 + ni * 16 + r;
      bf[ni] = *(const short8*)(bb + row * 32 + ((g * 8) ^ ((row & 3) << 3)));
    }
#pragma unroll
    for (int mi = 0; mi < MI; ++mi)
#pragma unroll
      for (int ni = 0; ni < 4; ++ni) {
        if constexpr (SWAP)
          acc[mi][ni] = __builtin_amdgcn_mfma_f32_16x16x32_bf16(bf[ni], af[mi], acc[mi][ni], 0, 0, 0);
        else
          acc[mi][ni] = __builtin_amdgcn_mfma_f32_16x16x32_bf16(af[mi], bf[ni], acc[mi][ni], 0, 0, 0);
      }
  }

  if constexpr (!SWAP) {
    // EPI 3: lane owns col = n0+wc*64+ni*16+r (fixed), rows rowb+0..3
#pragma unroll
    for (int mi = 0; mi < MI; ++mi)
#pragma unroll
      for (int ni = 0; ni < 4; ++ni) {
        const int rowb = m0 + wr * (MT / 2) + mi * 16 + 4 * g;
        const int col = n0 + wc * 64 + ni * 16 + r;
        u16 pk[4];
#pragma unroll
        for (int j = 0; j < 4; ++j) pk[j] = f2bf(acc[mi][ni][j]);
        if (col < 1536) {
#pragma unroll
          for (int j = 0; j < 4; ++j)
            ((u16*)Cp)[(size_t)(rowb + j) * N + col] = pk[j];
        } else {
          uint2 w2;
          w2.x = (uint32_t)pk[0] | ((uint32_t)pk[1] << 16);
          w2.y = (uint32_t)pk[2] | ((uint32_t)pk[3] << 16);
          *(uint2*)(vTp + (size_t)(col - 1536) * NTOK + rowb) = w2;
        }
      }
  } else {
    // SWAP epilogue: lane owns m (fixed), 4 consecutive cols nb..nb+3
#pragma unroll
    for (int mi = 0; mi < MI; ++mi) {
      const int m = m0 + wr * (MT / 2) + mi * 16 + r;
#pragma unroll
      for (int ni = 0; ni < 4; ++ni) {
        const int nb = n0 + wc * 64 + ni * 16 + 4 * g;
        if constexpr (EPI == 2) {
          const float4 bs = *(const float4*)(bias + nb);
          float tj[4];
#pragma unroll
          for (int j = 0; j < 4; ++j) {
            float t = acc[mi][ni][j] + (&bs.x)[j];
            float e = __expf(1.5957691216057308f * (t + 0.044715f * t * t * t));
            tj[j] = 0.5f * t * (1.f + (1.f - 2.f / (e + 1.f)));
          }
          uint2 w2;
          w2.x = pkbf(tj[0], tj[1]);
          w2.y = pkbf(tj[2], tj[3]);
          *(uint2*)((u16*)Cp + (size_t)m * N + nb) = w2;
        } else if constexpr (EPI == 4) {
          const float4 bs = *(const float4*)(bias + nb);
          const float4 rs = *(const float4*)(res + (size_t)m * N + nb);
          uint2 w2;
          w2.x = pkbf(acc[mi][ni][0] + bs.x + rs.x, acc[mi][ni][1] + bs.y + rs.y);
          w2.y = pkbf(acc[mi][ni][2] + bs.z + rs.z, acc[mi][ni][3] + bs.w + rs.w);
          *(uint2*)((u16*)Cp + (size_t)m * N + nb) = w2;
        } else {  // EPI 5
          const float4 bs = *(const float4*)(bias + nb);
          const uint2 r2 = *(const uint2*)(res16 + (size_t)m * N + nb);
          float4 o;
          o.x = acc[mi][ni][0] + bs.x + bf2f(r2.x & 0xffffu);
          o.y = acc[mi][ni][1] + bs.y + bf2f(r2.x >> 16);
          o.z = acc[mi][ni][2] + bs.z + bf2f(r2.y & 0xffffu);
          o.w = acc[mi][ni][3] + bs.w + bf2f(r2.y >> 16);
          *(float4*)((float*)Cp + (size_t)m * N + nb) = o;
        }
      }
    }
  }
}

// ---------------- flash attention, causal, QBLK=128, swapped-QK^T --------
#define CEXP 0.18033688011112042f  /* log2(e)/8 */

__global__ __launch_bounds__(256, 3)
void attn_kernel(const u16* __restrict__ qkv, const u16* __restrict__ vT,
                 u16* __restrict__ ctx) {
  const int bh = blockIdx.x;
  const int qt = blockIdx.y;
  const int b = bh / NHEAD, h = bh % NHEAD;
  const int tid = threadIdx.x;
  const int wave = tid >> 6, lane = tid & 63;
  const int r = lane & 15, g = lane >> 4;

  __shared__ u16 Kb[2][64 * 64];
  __shared__ u16 Vb[2][64 * 64];
  __shared__ u16 Pt[4][16 * 64];

  const int qw = qt * 128 + wave * 32;
  const int tok0 = b * SEQ;

  short8 aq[2][2];
#pragma unroll
  for (int qf = 0; qf < 2; ++qf) {
    const u16* qb = qkv + (size_t)(tok0 + qw + qf * 16 + r) * QKVW + h * HD;
    aq[qf][0] = *(const short8*)(qb + g * 8);
    aq[qf][1] = *(const short8*)(qb + 32 + g * 8);
  }

  float l_st[2] = {0.f, 0.f};
  f32x4 oc[2][4] = {};

  const int sr = tid >> 3;
  const int sc = (tid & 7) * 8;
  const int nt = 2 * qt + 2;

  const u16* kg = qkv + (size_t)tok0 * QKVW + EMB + h * HD;
  const u16* vg = vT + (size_t)(h * HD) * NTOK + tok0;
  const int e0 = sc ^ ((sr & 7) << 3);

  auto stage = [&](int buf, int kt) {
    const size_t koff = (size_t)kt * 64;
    u16* kb = (u16*)Kb[buf] + wave * 512;
    u16* vb = (u16*)Vb[buf] + wave * 512;
    g2l16(kg + (koff + sr) * QKVW + e0, kb);
    g2l16(kg + (koff + sr + 32) * QKVW + e0, kb + 2048);
    g2l16(vg + (size_t)sr * NTOK + koff + e0, vb);
    g2l16(vg + (size_t)(sr + 32) * NTOK + koff + e0, vb + 2048);
  };

  stage(0, 0);
  for (int kb = 0; kb < nt; ++kb) {
    __syncthreads();
    const int cur = kb & 1;
    if (kb + 1 < nt) stage(cur ^ 1, kb + 1);

    const int kv0 = kb * 64;
    if (kv0 > qw + 31) continue;

    short8 kf[4][2];
#pragma unroll
    for (int nf = 0; nf < 4; ++nf) {
      const int row = nf * 16 + r;
#pragma unroll
      for (int kk = 0; kk < 2; ++kk)
        kf[nf][kk] = *(const short8*)((char*)Kb[cur] + row * 128 +
                                      ((kk * 64 + g * 16) ^ ((row & 7) << 4)));
    }
    short8 bv[2][4];
#pragma unroll
    for (int half = 0; half < 2; ++half)
#pragma unroll
      for (int nd = 0; nd < 4; ++nd) {
        const int vr = nd * 16 + r;
        bv[half][nd] = *(const short8*)((char*)Vb[cur] + vr * 128 +
                       ((half * 64 + g * 16) ^ ((vr & 7) << 4)));
      }

#pragma unroll
    for (int qf = 0; qf < 2; ++qf) {
      f32x4 st[4];
#pragma unroll
      for (int nf = 0; nf < 4; ++nf) {
        f32x4 z = {};
        z = __builtin_amdgcn_mfma_f32_16x16x32_bf16(kf[nf][0], aq[qf][0], z, 0, 0, 0);
        z = __builtin_amdgcn_mfma_f32_16x16x32_bf16(kf[nf][1], aq[qf][1], z, 0, 0, 0);
        st[nf] = z;
      }
      if (kv0 + 63 > qw + qf * 16) {
        const int qg = qw + qf * 16 + r;
#pragma unroll
        for (int nf = 0; nf < 4; ++nf)
#pragma unroll
          for (int j = 0; j < 4; ++j)
            if (kv0 + nf * 16 + 4 * g + j > qg) st[nf][j] = -3e38f;
      }
      float p[4][4];
      float ps = 0.f;
#pragma unroll
      for (int nf = 0; nf < 4; ++nf)
#pragma unroll
        for (int j = 0; j < 4; ++j) {
          const float pe = exp2f(st[nf][j] * CEXP);
          p[nf][j] = pe;
          ps += pe;
        }
      ps += __shfl_xor(ps, 16);
      ps += __shfl_xor(ps, 32);
      l_st[qf] += ps;

      u16* Pw = (u16*)Pt[wave];
#pragma unroll
      for (int nf = 0; nf < 4; ++nf) {
        uint2 w2;
        w2.x = pkbf(p[nf][0], p[nf][1]);
        w2.y = pkbf(p[nf][2], p[nf][3]);
        *(uint2*)((char*)Pw + r * 128 + ((nf * 32 + g * 8) ^ ((r & 7) << 4))) = w2;
      }
#pragma unroll
      for (int half = 0; half < 2; ++half) {
        short8 pa = *(const short8*)((char*)Pw + r * 128 +
                                     ((half * 64 + g * 16) ^ ((r & 7) << 4)));
#pragma unroll
        for (int nd = 0; nd < 4; ++nd)
          oc[qf][nd] = __builtin_amdgcn_mfma_f32_16x16x32_bf16(pa, bv[half][nd], oc[qf][nd], 0, 0, 0);
      }
    }
  }

#pragma unroll
  for (int qf = 0; qf < 2; ++qf) {
    const float rl = 1.f / l_st[qf];
#pragma unroll
    for (int j = 0; j < 4; ++j) {
      const float rj = __shfl(rl, 4 * g + j, 16);
      const size_t row = (size_t)tok0 + qw + qf * 16 + 4 * g + j;
#pragma unroll
      for (int nd = 0; nd < 4; ++nd)
        ctx[row * EMB + h * HD + nd * 16 + r] = f2bf(oc[qf][nd][j] * rj);
    }
  }
}

extern "C" void kernel_launch(void* const* d_in, const int* in_sizes, int n_in,
                              void* d_out, int out_size, void* d_ws, size_t ws_size,
                              hipStream_t stream) {
  const float* x    = (const float*)d_in[0];
  const float* Wq   = (const float*)d_in[1];
  const float* Wk   = (const float*)d_in[2];
  const float* Wv   = (const float*)d_in[3];
  const float* Wo   = (const float*)d_in[4];
  const float* bo   = (const float*)d_in[5];
  const float* W1   = (const float*)d_in[6];
  const float* b1   = (const float*)d_in[7];
  const float* W2   = (const float*)d_in[8];
  const float* b2   = (const float*)d_in[9];
  const float* ln1s = (const float*)d_in[10];
  const float* ln1b = (const float*)d_in[11];
  const float* ln2s = (const float*)d_in[12];
  const float* ln2b = (const float*)d_in[13];

  char* p = (char*)d_ws;
  u16* qkvT = (u16*)p; p += (size_t)QKVW * EMB * 2;
  u16* woT  = (u16*)p; p += (size_t)EMB * EMB * 2;
  u16* w1T  = (u16*)p; p += (size_t)FFD * EMB * 2;
  u16* w2T  = (u16*)p; p += (size_t)EMB * FFD * 2;
  u16* h1   = (u16*)p; p += (size_t)NTOK * EMB * 2;
  u16* qkv  = (u16*)p; p += (size_t)NTOK * QKVW * 2;
  u16* x2bf = (u16*)p; p += (size_t)NTOK * EMB * 2;
  u16* ff1  = (u16*)p; p += (size_t)NTOK * FFD * 2;
  u16* ctxb = h1;        // h1 dead after QKV GEMM
  u16* h2   = qkv;       // qkv dead after attention
  u16* vT   = ff1;       // vT lives [QKV GEMM, attn); ff1 lives [FF1 GEMM, end)

  if (ws_size < (size_t)(p - (char*)d_ws)) return;

  dim3 blk(256);
  prep_kernel<<<8960, blk, 0, stream>>>(Wq, Wk, Wv, Wo, W1, W2, qkvT, woT, w1T, w2T,
                                        x, ln1s, ln1b, h1);
  gemm_kernel<3, 128, false><<<dim3(18, 64), blk, 0, stream>>>(h1, qkvT, qkv, nullptr, nullptr, nullptr, vT, NTOK, QKVW, EMB);
  attn_kernel<<<dim3(96, 8), blk, 0, stream>>>(qkv, vT, ctxb);
  gemm_kernel<4, 64, true><<<dim3(6, 128), blk, 0, stream>>>(ctxb, woT, x2bf, bo, x, nullptr, nullptr, NTOK, EMB, EMB);
  ln_bf_vec_kernel<<<NTOK / 4, blk, 0, stream>>>(x2bf, ln2s, ln2b, h2);
  gemm_kernel<2, 128, true><<<dim3(24, 64), blk, 0, stream>>>(h2, w1T, ff1, b1, nullptr, nullptr, nullptr, NTOK, FFD, EMB);
  gemm_kernel<5, 64, true><<<dim3(6, 128), blk, 0, stream>>>(ff1, w2T, (float*)d_out, b2, nullptr, x2bf, nullptr, NTOK, EMB, FFD);
}

// Round 12
// 260.521 us; speedup vs baseline: 1.0754x; 1.0754x over previous
//
#include <hip/hip_runtime.h>
#include <hip/hip_bf16.h>
#include <stdint.h>
#include <stddef.h>

#define EMB 768
#define FFD 3072
#define NHEAD 12
#define HD 64
#define SEQ 1024
#define NTOK 8192
#define QKVW 2304

typedef unsigned short u16;
typedef __attribute__((ext_vector_type(8))) short short8;
typedef __attribute__((ext_vector_type(4))) float f32x4;

__device__ __forceinline__ u16 f2bf(float f) {
  union { float f; uint32_t u; } w; w.f = f;
  uint32_t x = w.u + 0x7fffu + ((w.u >> 16) & 1u);
  return (u16)(x >> 16);
}

__device__ __forceinline__ float bf2f(uint32_t v) {
  union { uint32_t u; float f; } c; c.u = v << 16; return c.f;
}

__device__ __forceinline__ uint32_t pkbf(float lo, float hi) {
  __hip_bfloat162 h = __float22bfloat162_rn(float2{lo, hi});
  union { __hip_bfloat162 h; uint32_t u; } cv; cv.h = h;
  return cv.u;
}

__device__ __forceinline__ void g2l16(const void* g, void* l) {
  __builtin_amdgcn_global_load_lds(
      (const __attribute__((address_space(1))) void*)g,
      (__attribute__((address_space(3))) void*)l, 16, 0, 0);
}

// ------------- prep kernel: 6 weight transposes + LN1, flat block decode ------
__global__ __launch_bounds__(256)
void prep_kernel(const float* __restrict__ Wq, const float* __restrict__ Wk,
                 const float* __restrict__ Wv, const float* __restrict__ Wo,
                 const float* __restrict__ W1, const float* __restrict__ W2,
                 u16* __restrict__ qkvT, u16* __restrict__ woT,
                 u16* __restrict__ w1T, u16* __restrict__ w2T,
                 const float* __restrict__ x, const float* __restrict__ sc,
                 const float* __restrict__ sh, u16* __restrict__ h1) {
  __shared__ float tile[32][33];
  const int id = blockIdx.x;
  if (id >= 6912) {
    const int wave = threadIdx.x >> 6, lane = threadIdx.x & 63;
    const int row = (id - 6912) * 4 + wave;
    const float* xr = x + (size_t)row * EMB;
    float4 v[3];
    float s = 0.f, ss = 0.f;
#pragma unroll
    for (int i = 0; i < 3; ++i) {
      v[i] = *(const float4*)(xr + lane * 4 + i * 256);
      s += v[i].x + v[i].y + v[i].z + v[i].w;
      ss += v[i].x * v[i].x + v[i].y * v[i].y + v[i].z * v[i].z + v[i].w * v[i].w;
    }
#pragma unroll
    for (int m = 1; m < 64; m <<= 1) { s += __shfl_xor(s, m, 64); ss += __shfl_xor(ss, m, 64); }
    const float mean = s * (1.f / EMB);
    const float inv = rsqrtf(ss * (1.f / EMB) - mean * mean + 1e-5f);
    u16* orow = h1 + (size_t)row * EMB;
#pragma unroll
    for (int i = 0; i < 3; ++i) {
      const int c = lane * 4 + i * 256;
      const float4 s4 = *(const float4*)(sc + c);
      const float4 h4 = *(const float4*)(sh + c);
      uint2 w2;
      w2.x = pkbf((v[i].x - mean) * inv * s4.x + h4.x, (v[i].y - mean) * inv * s4.y + h4.y);
      w2.y = pkbf((v[i].z - mean) * inv * s4.z + h4.z, (v[i].w - mean) * inv * s4.w + h4.w);
      *(uint2*)(orow + c) = w2;
    }
    return;
  }
  const float* in; u16* out; int K, N, bx, by;
  if (id < 1728) {
    const int z = id / 576, rem = id % 576;
    in = z == 0 ? Wq : (z == 1 ? Wk : Wv);
    out = qkvT + (size_t)z * EMB * EMB;
    K = EMB; N = EMB; bx = rem % 24; by = rem / 24;
  } else if (id < 2304) {
    const int rem = id - 1728;
    in = Wo; out = woT; K = EMB; N = EMB; bx = rem % 24; by = rem / 24;
  } else if (id < 4608) {
    const int rem = id - 2304;
    in = W1; out = w1T; K = EMB; N = FFD; bx = rem % 96; by = rem / 96;
  } else {
    const int rem = id - 4608;
    in = W2; out = w2T; K = FFD; N = EMB; bx = rem % 24; by = rem / 24;
  }
  const int n0 = bx * 32, k0 = by * 32;
  const int tx = threadIdx.x & 31;
  const int ty = threadIdx.x >> 5;
#pragma unroll
  for (int i = 0; i < 32; i += 8)
    tile[ty + i][tx] = in[(size_t)(k0 + ty + i) * N + n0 + tx];
  __syncthreads();
#pragma unroll
  for (int i = 0; i < 32; i += 8)
    out[(size_t)(n0 + ty + i) * K + k0 + tx] = f2bf(tile[tx][ty + i]);
}

// layernorm, wave-per-row, vectorized (bf16 in)
__global__ __launch_bounds__(256)
void ln_bf_vec_kernel(const u16* __restrict__ x, const float* __restrict__ sc,
                      const float* __restrict__ sh, u16* __restrict__ out) {
  const int wave = threadIdx.x >> 6, lane = threadIdx.x & 63;
  const int row = blockIdx.x * 4 + wave;
  const u16* xr = x + (size_t)row * EMB;
  float v[3][4];
  float s = 0.f, ss = 0.f;
#pragma unroll
  for (int i = 0; i < 3; ++i) {
    const uint2 r2 = *(const uint2*)(xr + lane * 4 + i * 256);
    v[i][0] = bf2f(r2.x & 0xffffu);
    v[i][1] = bf2f(r2.x >> 16);
    v[i][2] = bf2f(r2.y & 0xffffu);
    v[i][3] = bf2f(r2.y >> 16);
#pragma unroll
    for (int j = 0; j < 4; ++j) { s += v[i][j]; ss += v[i][j] * v[i][j]; }
  }
#pragma unroll
  for (int m = 1; m < 64; m <<= 1) { s += __shfl_xor(s, m, 64); ss += __shfl_xor(ss, m, 64); }
  const float mean = s * (1.f / EMB);
  const float inv = rsqrtf(ss * (1.f / EMB) - mean * mean + 1e-5f);
  u16* orow = out + (size_t)row * EMB;
#pragma unroll
  for (int i = 0; i < 3; ++i) {
    const int c = lane * 4 + i * 256;
    const float4 s4 = *(const float4*)(sc + c);
    const float4 h4 = *(const float4*)(sh + c);
    uint2 w2;
    w2.x = pkbf((v[i][0] - mean) * inv * s4.x + h4.x, (v[i][1] - mean) * inv * s4.y + h4.y);
    w2.y = pkbf((v[i][2] - mean) * inv * s4.z + h4.z, (v[i][3] - mean) * inv * s4.w + h4.w);
    *(uint2*)(orow + c) = w2;
  }
}

// ---------------- bf16 GEMM: C[M,N] = A[M,K] @ BT[N,K]^T ----------------
// r10/r7 mainloop (single-buffered, 16x16x32, BK=64, conflict-free swizzle).
// NEW: column-major tile mapping -- each XCD's contiguous swz chunk becomes an
// n-column slab (B-slab stays L2-resident, A streams) -- and min-4-blocks/CU
// launch bound for stall overlap.
// SWAP=true: mfma(bf, af) -> lane holds one M-row, 4 consecutive N-cols.
// EPI 2 (SWAP): C bf16 = gelu_tanh(acc + bias[n])          (uint2 st)
// EPI 4 (SWAP): C bf16 = acc + bias[n] + resf32[m*N+n]     (uint2 st)
// EPI 5 (SWAP): C f32  = acc + bias[n] + bf2f(res16[...])  (float4 st)
// EPI 3 (!SWAP): QKV split (cols<1536 row-major bf16; V cols -> vTp transposed)
template <int EPI, int MT, bool SWAP>
__global__ __launch_bounds__(256, 4)
void gemm_kernel(const u16* __restrict__ A, const u16* __restrict__ BT,
                 void* __restrict__ Cp, const float* __restrict__ bias,
                 const float* __restrict__ res, const u16* __restrict__ res16,
                 u16* __restrict__ vTp, int M, int N, int K) {
  constexpr int MI = MT / 32;
  __shared__ u16 As[MT * 64];
  __shared__ u16 Bs[128 * 64];

  const int nwg = gridDim.x * gridDim.y;
  const int orig = blockIdx.y * gridDim.x + blockIdx.x;
  const int swz = (orig & 7) * (nwg >> 3) + (orig >> 3);
  // column-major tile decode: consecutive swz walk M first -> XCD owns n-slab
  const int m0 = (swz % gridDim.y) * MT;
  const int n0 = (swz / gridDim.y) * 128;

  const int tid = threadIdx.x;
  const int wave = tid >> 6, lane = tid & 63;
  const int wr = wave >> 1, wc = wave & 1;
  const int r = lane & 15, g = lane >> 4;
  const int lrow = lane >> 3;
  const int lelem = (lane & 7) * 8;

  f32x4 acc[MI][4] = {};

  const int nkt = K >> 6;
  for (int kt = 0; kt < nkt; ++kt) {
    const int k0 = kt << 6;
    if (kt) __syncthreads();
#pragma unroll
    for (int q = 0; q < MT / 32; ++q) {
      const int chunk = q * 4 + wave;
      const int row = chunk * 8 + lrow;
      const int e = lelem ^ ((row & 7) << 3);
      g2l16(A + (size_t)(m0 + row) * K + k0 + e, As + chunk * 512);
    }
#pragma unroll
    for (int q = 0; q < 4; ++q) {
      const int chunk = q * 4 + wave;
      const int row = chunk * 8 + lrow;
      const int e = lelem ^ ((row & 7) << 3);
      g2l16(BT + (size_t)(n0 + row) * K + k0 + e, Bs + chunk * 512);
    }
    __syncthreads();
#pragma unroll
    for (int kk = 0; kk < 2; ++kk) {
      short8 af[MI], bf[4];
#pragma unroll
      for (int mi = 0; mi < MI; ++mi) {
        const int row = wr * (MT / 2) + mi * 16 + r;
        af[mi] = *(const short8*)(As + row * 64 + ((kk * 32 + g * 8) ^ ((row & 7) << 3)));
      }
#pragma unroll
      for (int ni = 0; ni < 4; ++ni) {
        const int row = wc * 64 + ni * 16 + r;
        bf[ni] = *(const short8*)(Bs + row * 64 + ((kk * 32 + g * 8) ^ ((row & 7) << 3)));
      }
#pragma unroll
      for (int mi = 0; mi < MI; ++mi)
#pragma unroll
        for (int ni = 0; ni < 4; ++ni) {
          if constexpr (SWAP)
            acc[mi][ni] = __builtin_amdgcn_mfma_f32_16x16x32_bf16(bf[ni], af[mi], acc[mi][ni], 0, 0, 0);
          else
            acc[mi][ni] = __builtin_amdgcn_mfma_f32_16x16x32_bf16(af[mi], bf[ni], acc[mi][ni], 0, 0, 0);
        }
    }
  }

  if constexpr (!SWAP) {
    // EPI 3: lane owns col = n0+wc*64+ni*16+r (fixed), rows rowb+0..3
#pragma unroll
    for (int mi = 0; mi < MI; ++mi)
#pragma unroll
      for (int ni = 0; ni < 4; ++ni) {
        const int rowb = m0 + wr * (MT / 2) + mi * 16 + 4 * g;
        const int col = n0 + wc * 64 + ni * 16 + r;
        u16 pk[4];
#pragma unroll
        for (int j = 0; j < 4; ++j) pk[j] = f2bf(acc[mi][ni][j]);
        if (col < 1536) {
#pragma unroll
          for (int j = 0; j < 4; ++j)
            ((u16*)Cp)[(size_t)(rowb + j) * N + col] = pk[j];
        } else {
          uint2 w2;
          w2.x = (uint32_t)pk[0] | ((uint32_t)pk[1] << 16);
          w2.y = (uint32_t)pk[2] | ((uint32_t)pk[3] << 16);
          *(uint2*)(vTp + (size_t)(col - 1536) * NTOK + rowb) = w2;
        }
      }
  } else {
    // SWAP epilogue: lane owns m (fixed), 4 consecutive cols nb..nb+3
#pragma unroll
    for (int mi = 0; mi < MI; ++mi) {
      const int m = m0 + wr * (MT / 2) + mi * 16 + r;
#pragma unroll
      for (int ni = 0; ni < 4; ++ni) {
        const int nb = n0 + wc * 64 + ni * 16 + 4 * g;
        if constexpr (EPI == 2) {
          const float4 bs = *(const float4*)(bias + nb);
          float tj[4];
#pragma unroll
          for (int j = 0; j < 4; ++j) {
            float t = acc[mi][ni][j] + (&bs.x)[j];
            float e = __expf(1.5957691216057308f * (t + 0.044715f * t * t * t));
            tj[j] = 0.5f * t * (1.f + (1.f - 2.f / (e + 1.f)));
          }
          uint2 w2;
          w2.x = pkbf(tj[0], tj[1]);
          w2.y = pkbf(tj[2], tj[3]);
          *(uint2*)((u16*)Cp + (size_t)m * N + nb) = w2;
        } else if constexpr (EPI == 4) {
          const float4 bs = *(const float4*)(bias + nb);
          const float4 rs = *(const float4*)(res + (size_t)m * N + nb);
          uint2 w2;
          w2.x = pkbf(acc[mi][ni][0] + bs.x + rs.x, acc[mi][ni][1] + bs.y + rs.y);
          w2.y = pkbf(acc[mi][ni][2] + bs.z + rs.z, acc[mi][ni][3] + bs.w + rs.w);
          *(uint2*)((u16*)Cp + (size_t)m * N + nb) = w2;
        } else {  // EPI 5
          const float4 bs = *(const float4*)(bias + nb);
          const uint2 r2 = *(const uint2*)(res16 + (size_t)m * N + nb);
          float4 o;
          o.x = acc[mi][ni][0] + bs.x + bf2f(r2.x & 0xffffu);
          o.y = acc[mi][ni][1] + bs.y + bf2f(r2.x >> 16);
          o.z = acc[mi][ni][2] + bs.z + bf2f(r2.y & 0xffffu);
          o.w = acc[mi][ni][3] + bs.w + bf2f(r2.y >> 16);
          *(float4*)((float*)Cp + (size_t)m * N + nb) = o;
        }
      }
    }
  }
}

// ---------------- flash attention, causal, QBLK=128, swapped-QK^T --------
#define CEXP 0.18033688011112042f  /* log2(e)/8 */

__global__ __launch_bounds__(256, 3)
void attn_kernel(const u16* __restrict__ qkv, const u16* __restrict__ vT,
                 u16* __restrict__ ctx) {
  const int bh = blockIdx.x;
  const int qt = blockIdx.y;
  const int b = bh / NHEAD, h = bh % NHEAD;
  const int tid = threadIdx.x;
  const int wave = tid >> 6, lane = tid & 63;
  const int r = lane & 15, g = lane >> 4;

  __shared__ u16 Kb[2][64 * 64];
  __shared__ u16 Vb[2][64 * 64];
  __shared__ u16 Pt[4][16 * 64];

  const int qw = qt * 128 + wave * 32;
  const int tok0 = b * SEQ;

  short8 aq[2][2];
#pragma unroll
  for (int qf = 0; qf < 2; ++qf) {
    const u16* qb = qkv + (size_t)(tok0 + qw + qf * 16 + r) * QKVW + h * HD;
    aq[qf][0] = *(const short8*)(qb + g * 8);
    aq[qf][1] = *(const short8*)(qb + 32 + g * 8);
  }

  float l_st[2] = {0.f, 0.f};
  f32x4 oc[2][4] = {};

  const int sr = tid >> 3;
  const int sc = (tid & 7) * 8;
  const int nt = 2 * qt + 2;

  const u16* kg = qkv + (size_t)tok0 * QKVW + EMB + h * HD;
  const u16* vg = vT + (size_t)(h * HD) * NTOK + tok0;
  const int e0 = sc ^ ((sr & 7) << 3);

  auto stage = [&](int buf, int kt) {
    const size_t koff = (size_t)kt * 64;
    u16* kb = (u16*)Kb[buf] + wave * 512;
    u16* vb = (u16*)Vb[buf] + wave * 512;
    g2l16(kg + (koff + sr) * QKVW + e0, kb);
    g2l16(kg + (koff + sr + 32) * QKVW + e0, kb + 2048);
    g2l16(vg + (size_t)sr * NTOK + koff + e0, vb);
    g2l16(vg + (size_t)(sr + 32) * NTOK + koff + e0, vb + 2048);
  };

  stage(0, 0);
  for (int kb = 0; kb < nt; ++kb) {
    __syncthreads();
    const int cur = kb & 1;
    if (kb + 1 < nt) stage(cur ^ 1, kb + 1);

    const int kv0 = kb * 64;
    if (kv0 > qw + 31) continue;

    short8 kf[4][2];
#pragma unroll
    for (int nf = 0; nf < 4; ++nf) {
      const int row = nf * 16 + r;
#pragma unroll
      for (int kk = 0; kk < 2; ++kk)
        kf[nf][kk] = *(const short8*)((char*)Kb[cur] + row * 128 +
                                      ((kk * 64 + g * 16) ^ ((row & 7) << 4)));
    }
    short8 bv[2][4];
#pragma unroll
    for (int half = 0; half < 2; ++half)
#pragma unroll
      for (int nd = 0; nd < 4; ++nd) {
        const int vr = nd * 16 + r;
        bv[half][nd] = *(const short8*)((char*)Vb[cur] + vr * 128 +
                       ((half * 64 + g * 16) ^ ((vr & 7) << 4)));
      }

#pragma unroll
    for (int qf = 0; qf < 2; ++qf) {
      f32x4 st[4];
#pragma unroll
      for (int nf = 0; nf < 4; ++nf) {
        f32x4 z = {};
        z = __builtin_amdgcn_mfma_f32_16x16x32_bf16(kf[nf][0], aq[qf][0], z, 0, 0, 0);
        z = __builtin_amdgcn_mfma_f32_16x16x32_bf16(kf[nf][1], aq[qf][1], z, 0, 0, 0);
        st[nf] = z;
      }
      if (kv0 + 63 > qw + qf * 16) {
        const int qg = qw + qf * 16 + r;
#pragma unroll
        for (int nf = 0; nf < 4; ++nf)
#pragma unroll
          for (int j = 0; j < 4; ++j)
            if (kv0 + nf * 16 + 4 * g + j > qg) st[nf][j] = -3e38f;
      }
      float p[4][4];
      float ps = 0.f;
#pragma unroll
      for (int nf = 0; nf < 4; ++nf)
#pragma unroll
        for (int j = 0; j < 4; ++j) {
          const float pe = exp2f(st[nf][j] * CEXP);
          p[nf][j] = pe;
          ps += pe;
        }
      ps += __shfl_xor(ps, 16);
      ps += __shfl_xor(ps, 32);
      l_st[qf] += ps;

      u16* Pw = (u16*)Pt[wave];
#pragma unroll
      for (int nf = 0; nf < 4; ++nf) {
        uint2 w2;
        w2.x = pkbf(p[nf][0], p[nf][1]);
        w2.y = pkbf(p[nf][2], p[nf][3]);
        *(uint2*)((char*)Pw + r * 128 + ((nf * 32 + g * 8) ^ ((r & 7) << 4))) = w2;
      }
#pragma unroll
      for (int half = 0; half < 2; ++half) {
        short8 pa = *(const short8*)((char*)Pw + r * 128 +
                                     ((half * 64 + g * 16) ^ ((r & 7) << 4)));
#pragma unroll
        for (int nd = 0; nd < 4; ++nd)
          oc[qf][nd] = __builtin_amdgcn_mfma_f32_16x16x32_bf16(pa, bv[half][nd], oc[qf][nd], 0, 0, 0);
      }
    }
  }

#pragma unroll
  for (int qf = 0; qf < 2; ++qf) {
    const float rl = 1.f / l_st[qf];
#pragma unroll
    for (int j = 0; j < 4; ++j) {
      const float rj = __shfl(rl, 4 * g + j, 16);
      const size_t row = (size_t)tok0 + qw + qf * 16 + 4 * g + j;
#pragma unroll
      for (int nd = 0; nd < 4; ++nd)
        ctx[row * EMB + h * HD + nd * 16 + r] = f2bf(oc[qf][nd][j] * rj);
    }
  }
}

extern "C" void kernel_launch(void* const* d_in, const int* in_sizes, int n_in,
                              void* d_out, int out_size, void* d_ws, size_t ws_size,
                              hipStream_t stream) {
  const float* x    = (const float*)d_in[0];
  const float* Wq   = (const float*)d_in[1];
  const float* Wk   = (const float*)d_in[2];
  const float* Wv   = (const float*)d_in[3];
  const float* Wo   = (const float*)d_in[4];
  const float* bo   = (const float*)d_in[5];
  const float* W1   = (const float*)d_in[6];
  const float* b1   = (const float*)d_in[7];
  const float* W2   = (const float*)d_in[8];
  const float* b2   = (const float*)d_in[9];
  const float* ln1s = (const float*)d_in[10];
  const float* ln1b = (const float*)d_in[11];
  const float* ln2s = (const float*)d_in[12];
  const float* ln2b = (const float*)d_in[13];

  char* p = (char*)d_ws;
  u16* qkvT = (u16*)p; p += (size_t)QKVW * EMB * 2;
  u16* woT  = (u16*)p; p += (size_t)EMB * EMB * 2;
  u16* w1T  = (u16*)p; p += (size_t)FFD * EMB * 2;
  u16* w2T  = (u16*)p; p += (size_t)EMB * FFD * 2;
  u16* h1   = (u16*)p; p += (size_t)NTOK * EMB * 2;
  u16* qkv  = (u16*)p; p += (size_t)NTOK * QKVW * 2;
  u16* x2bf = (u16*)p; p += (size_t)NTOK * EMB * 2;
  u16* ff1  = (u16*)p; p += (size_t)NTOK * FFD * 2;
  u16* ctxb = h1;        // h1 dead after QKV GEMM
  u16* h2   = qkv;       // qkv dead after attention
  u16* vT   = ff1;       // vT lives [QKV GEMM, attn); ff1 lives [FF1 GEMM, end)

  if (ws_size < (size_t)(p - (char*)d_ws)) return;

  dim3 blk(256);
  prep_kernel<<<8960, blk, 0, stream>>>(Wq, Wk, Wv, Wo, W1, W2, qkvT, woT, w1T, w2T,
                                        x, ln1s, ln1b, h1);
  gemm_kernel<3, 128, false><<<dim3(18, 64), blk, 0, stream>>>(h1, qkvT, qkv, nullptr, nullptr, nullptr, vT, NTOK, QKVW, EMB);
  attn_kernel<<<dim3(96, 8), blk, 0, stream>>>(qkv, vT, ctxb);
  gemm_kernel<4, 64, true><<<dim3(6, 128), blk, 0, stream>>>(ctxb, woT, x2bf, bo, x, nullptr, nullptr, NTOK, EMB, EMB);
  ln_bf_vec_kernel<<<NTOK / 4, blk, 0, stream>>>(x2bf, ln2s, ln2b, h2);
  gemm_kernel<2, 128, true><<<dim3(24, 64), blk, 0, stream>>>(h2, w1T, ff1, b1, nullptr, nullptr, nullptr, NTOK, FFD, EMB);
  gemm_kernel<5, 64, true><<<dim3(6, 128), blk, 0, stream>>>(ff1, w2T, (float*)d_out, b2, nullptr, x2bf, nullptr, NTOK, EMB, FFD);
}

// Round 13
// 226.443 us; speedup vs baseline: 1.2372x; 1.1505x over previous
//
#include <hip/hip_runtime.h>
#include <hip/hip_bf16.h>
#include <stdint.h>
#include <stddef.h>

#define EMB 768
#define FFD 3072
#define NHEAD 12
#define HD 64
#define SEQ 1024
#define NTOK 8192
#define QKVW 2304

typedef unsigned short u16;
typedef __attribute__((ext_vector_type(8))) short short8;
typedef __attribute__((ext_vector_type(4))) float f32x4;

__device__ __forceinline__ u16 f2bf(float f) {
  union { float f; uint32_t u; } w; w.f = f;
  uint32_t x = w.u + 0x7fffu + ((w.u >> 16) & 1u);
  return (u16)(x >> 16);
}

__device__ __forceinline__ float bf2f(uint32_t v) {
  union { uint32_t u; float f; } c; c.u = v << 16; return c.f;
}

__device__ __forceinline__ uint32_t pkbf(float lo, float hi) {
  __hip_bfloat162 h = __float22bfloat162_rn(float2{lo, hi});
  union { __hip_bfloat162 h; uint32_t u; } cv; cv.h = h;
  return cv.u;
}

__device__ __forceinline__ void g2l16(const void* g, void* l) {
  __builtin_amdgcn_global_load_lds(
      (const __attribute__((address_space(1))) void*)g,
      (__attribute__((address_space(3))) void*)l, 16, 0, 0);
}

// ------------- prep kernel: 6 weight transposes + LN1, flat block decode ------
__global__ __launch_bounds__(256)
void prep_kernel(const float* __restrict__ Wq, const float* __restrict__ Wk,
                 const float* __restrict__ Wv, const float* __restrict__ Wo,
                 const float* __restrict__ W1, const float* __restrict__ W2,
                 u16* __restrict__ qkvT, u16* __restrict__ woT,
                 u16* __restrict__ w1T, u16* __restrict__ w2T,
                 const float* __restrict__ x, const float* __restrict__ sc,
                 const float* __restrict__ sh, u16* __restrict__ h1) {
  __shared__ float tile[32][33];
  const int id = blockIdx.x;
  if (id >= 6912) {
    const int wave = threadIdx.x >> 6, lane = threadIdx.x & 63;
    const int row = (id - 6912) * 4 + wave;
    const float* xr = x + (size_t)row * EMB;
    float4 v[3];
    float s = 0.f, ss = 0.f;
#pragma unroll
    for (int i = 0; i < 3; ++i) {
      v[i] = *(const float4*)(xr + lane * 4 + i * 256);
      s += v[i].x + v[i].y + v[i].z + v[i].w;
      ss += v[i].x * v[i].x + v[i].y * v[i].y + v[i].z * v[i].z + v[i].w * v[i].w;
    }
#pragma unroll
    for (int m = 1; m < 64; m <<= 1) { s += __shfl_xor(s, m, 64); ss += __shfl_xor(ss, m, 64); }
    const float mean = s * (1.f / EMB);
    const float inv = rsqrtf(ss * (1.f / EMB) - mean * mean + 1e-5f);
    u16* orow = h1 + (size_t)row * EMB;
#pragma unroll
    for (int i = 0; i < 3; ++i) {
      const int c = lane * 4 + i * 256;
      const float4 s4 = *(const float4*)(sc + c);
      const float4 h4 = *(const float4*)(sh + c);
      uint2 w2;
      w2.x = pkbf((v[i].x - mean) * inv * s4.x + h4.x, (v[i].y - mean) * inv * s4.y + h4.y);
      w2.y = pkbf((v[i].z - mean) * inv * s4.z + h4.z, (v[i].w - mean) * inv * s4.w + h4.w);
      *(uint2*)(orow + c) = w2;
    }
    return;
  }
  const float* in; u16* out; int K, N, bx, by;
  if (id < 1728) {
    const int z = id / 576, rem = id % 576;
    in = z == 0 ? Wq : (z == 1 ? Wk : Wv);
    out = qkvT + (size_t)z * EMB * EMB;
    K = EMB; N = EMB; bx = rem % 24; by = rem / 24;
  } else if (id < 2304) {
    const int rem = id - 1728;
    in = Wo; out = woT; K = EMB; N = EMB; bx = rem % 24; by = rem / 24;
  } else if (id < 4608) {
    const int rem = id - 2304;
    in = W1; out = w1T; K = EMB; N = FFD; bx = rem % 96; by = rem / 96;
  } else {
    const int rem = id - 4608;
    in = W2; out = w2T; K = FFD; N = EMB; bx = rem % 24; by = rem / 24;
  }
  const int n0 = bx * 32, k0 = by * 32;
  const int tx = threadIdx.x & 31;
  const int ty = threadIdx.x >> 5;
#pragma unroll
  for (int i = 0; i < 32; i += 8)
    tile[ty + i][tx] = in[(size_t)(k0 + ty + i) * N + n0 + tx];
  __syncthreads();
#pragma unroll
  for (int i = 0; i < 32; i += 8)
    out[(size_t)(n0 + ty + i) * K + k0 + tx] = f2bf(tile[tx][ty + i]);
}

// layernorm, wave-per-row, vectorized (bf16 in)
__global__ __launch_bounds__(256)
void ln_bf_vec_kernel(const u16* __restrict__ x, const float* __restrict__ sc,
                      const float* __restrict__ sh, u16* __restrict__ out) {
  const int wave = threadIdx.x >> 6, lane = threadIdx.x & 63;
  const int row = blockIdx.x * 4 + wave;
  const u16* xr = x + (size_t)row * EMB;
  float v[3][4];
  float s = 0.f, ss = 0.f;
#pragma unroll
  for (int i = 0; i < 3; ++i) {
    const uint2 r2 = *(const uint2*)(xr + lane * 4 + i * 256);
    v[i][0] = bf2f(r2.x & 0xffffu);
    v[i][1] = bf2f(r2.x >> 16);
    v[i][2] = bf2f(r2.y & 0xffffu);
    v[i][3] = bf2f(r2.y >> 16);
#pragma unroll
    for (int j = 0; j < 4; ++j) { s += v[i][j]; ss += v[i][j] * v[i][j]; }
  }
#pragma unroll
  for (int m = 1; m < 64; m <<= 1) { s += __shfl_xor(s, m, 64); ss += __shfl_xor(ss, m, 64); }
  const float mean = s * (1.f / EMB);
  const float inv = rsqrtf(ss * (1.f / EMB) - mean * mean + 1e-5f);
  u16* orow = out + (size_t)row * EMB;
#pragma unroll
  for (int i = 0; i < 3; ++i) {
    const int c = lane * 4 + i * 256;
    const float4 s4 = *(const float4*)(sc + c);
    const float4 h4 = *(const float4*)(sh + c);
    uint2 w2;
    w2.x = pkbf((v[i][0] - mean) * inv * s4.x + h4.x, (v[i][1] - mean) * inv * s4.y + h4.y);
    w2.y = pkbf((v[i][2] - mean) * inv * s4.z + h4.z, (v[i][3] - mean) * inv * s4.w + h4.w);
    *(uint2*)(orow + c) = w2;
  }
}

// ---------------- bf16 GEMM: C[M,N] = A[M,K] @ BT[N,K]^T ----------------
// r10 mainloop (single-buffered, 16x16x32, BK=64, conflict-free XOR swizzle,
// row-major XCD swizzle).  SWAP=true: mfma(bf, af) -> lane holds one M-row,
// 4 consecutive N-cols.
// EPI 2 (SWAP): C bf16 = gelu_tanh(acc + bias[n])          (uint2 st)
// EPI 4 (SWAP): C bf16 = acc + bias[n] + resf32[m*N+n]     (uint2 st)
// EPI 5 (SWAP): C f32  = acc + bias[n] + bf2f(res16[...])  (float4 st)
// EPI 6 (SWAP): C bf16 = acc (plain, stride N)             (uint2 st)  [QK]
// EPI 7 (!SWAP): vT[col][m] = acc (transposed)             (uint2 st)  [V]
template <int EPI, int MT, bool SWAP>
__global__ __launch_bounds__(256)
void gemm_kernel(const u16* __restrict__ A, const u16* __restrict__ BT,
                 void* __restrict__ Cp, const float* __restrict__ bias,
                 const float* __restrict__ res, const u16* __restrict__ res16,
                 u16* __restrict__ vTp, int M, int N, int K) {
  constexpr int MI = MT / 32;
  __shared__ u16 As[MT * 64];
  __shared__ u16 Bs[128 * 64];

  const int nwg = gridDim.x * gridDim.y;
  const int orig = blockIdx.y * gridDim.x + blockIdx.x;
  const int swz = (orig & 7) * (nwg >> 3) + (orig >> 3);
  const int m0 = (swz / gridDim.x) * MT;
  const int n0 = (swz % gridDim.x) * 128;

  const int tid = threadIdx.x;
  const int wave = tid >> 6, lane = tid & 63;
  const int wr = wave >> 1, wc = wave & 1;
  const int r = lane & 15, g = lane >> 4;
  const int lrow = lane >> 3;
  const int lelem = (lane & 7) * 8;

  f32x4 acc[MI][4] = {};

  const int nkt = K >> 6;
  for (int kt = 0; kt < nkt; ++kt) {
    const int k0 = kt << 6;
    if (kt) __syncthreads();
#pragma unroll
    for (int q = 0; q < MT / 32; ++q) {
      const int chunk = q * 4 + wave;
      const int row = chunk * 8 + lrow;
      const int e = lelem ^ ((row & 7) << 3);
      g2l16(A + (size_t)(m0 + row) * K + k0 + e, As + chunk * 512);
    }
#pragma unroll
    for (int q = 0; q < 4; ++q) {
      const int chunk = q * 4 + wave;
      const int row = chunk * 8 + lrow;
      const int e = lelem ^ ((row & 7) << 3);
      g2l16(BT + (size_t)(n0 + row) * K + k0 + e, Bs + chunk * 512);
    }
    __syncthreads();
#pragma unroll
    for (int kk = 0; kk < 2; ++kk) {
      short8 af[MI], bf[4];
#pragma unroll
      for (int mi = 0; mi < MI; ++mi) {
        const int row = wr * (MT / 2) + mi * 16 + r;
        af[mi] = *(const short8*)(As + row * 64 + ((kk * 32 + g * 8) ^ ((row & 7) << 3)));
      }
#pragma unroll
      for (int ni = 0; ni < 4; ++ni) {
        const int row = wc * 64 + ni * 16 + r;
        bf[ni] = *(const short8*)(Bs + row * 64 + ((kk * 32 + g * 8) ^ ((row & 7) << 3)));
      }
#pragma unroll
      for (int mi = 0; mi < MI; ++mi)
#pragma unroll
        for (int ni = 0; ni < 4; ++ni) {
          if constexpr (SWAP)
            acc[mi][ni] = __builtin_amdgcn_mfma_f32_16x16x32_bf16(bf[ni], af[mi], acc[mi][ni], 0, 0, 0);
          else
            acc[mi][ni] = __builtin_amdgcn_mfma_f32_16x16x32_bf16(af[mi], bf[ni], acc[mi][ni], 0, 0, 0);
        }
    }
  }

  if constexpr (!SWAP) {
    // EPI 7: lane owns col = n0+wc*64+ni*16+r (fixed), rows rowb+0..3 -> vT
#pragma unroll
    for (int mi = 0; mi < MI; ++mi)
#pragma unroll
      for (int ni = 0; ni < 4; ++ni) {
        const int rowb = m0 + wr * (MT / 2) + mi * 16 + 4 * g;
        const int col = n0 + wc * 64 + ni * 16 + r;
        uint2 w2;
        w2.x = pkbf(acc[mi][ni][0], acc[mi][ni][1]);
        w2.y = pkbf(acc[mi][ni][2], acc[mi][ni][3]);
        *(uint2*)(vTp + (size_t)col * NTOK + rowb) = w2;
      }
  } else {
    // SWAP epilogue: lane owns m (fixed), 4 consecutive cols nb..nb+3
#pragma unroll
    for (int mi = 0; mi < MI; ++mi) {
      const int m = m0 + wr * (MT / 2) + mi * 16 + r;
#pragma unroll
      for (int ni = 0; ni < 4; ++ni) {
        const int nb = n0 + wc * 64 + ni * 16 + 4 * g;
        if constexpr (EPI == 2) {
          const float4 bs = *(const float4*)(bias + nb);
          float tj[4];
#pragma unroll
          for (int j = 0; j < 4; ++j) {
            float t = acc[mi][ni][j] + (&bs.x)[j];
            float e = __expf(1.5957691216057308f * (t + 0.044715f * t * t * t));
            tj[j] = 0.5f * t * (1.f + (1.f - 2.f / (e + 1.f)));
          }
          uint2 w2;
          w2.x = pkbf(tj[0], tj[1]);
          w2.y = pkbf(tj[2], tj[3]);
          *(uint2*)((u16*)Cp + (size_t)m * N + nb) = w2;
        } else if constexpr (EPI == 4) {
          const float4 bs = *(const float4*)(bias + nb);
          const float4 rs = *(const float4*)(res + (size_t)m * N + nb);
          uint2 w2;
          w2.x = pkbf(acc[mi][ni][0] + bs.x + rs.x, acc[mi][ni][1] + bs.y + rs.y);
          w2.y = pkbf(acc[mi][ni][2] + bs.z + rs.z, acc[mi][ni][3] + bs.w + rs.w);
          *(uint2*)((u16*)Cp + (size_t)m * N + nb) = w2;
        } else if constexpr (EPI == 5) {
          const float4 bs = *(const float4*)(bias + nb);
          const uint2 r2 = *(const uint2*)(res16 + (size_t)m * N + nb);
          float4 o;
          o.x = acc[mi][ni][0] + bs.x + bf2f(r2.x & 0xffffu);
          o.y = acc[mi][ni][1] + bs.y + bf2f(r2.x >> 16);
          o.z = acc[mi][ni][2] + bs.z + bf2f(r2.y & 0xffffu);
          o.w = acc[mi][ni][3] + bs.w + bf2f(r2.y >> 16);
          *(float4*)((float*)Cp + (size_t)m * N + nb) = o;
        } else {  // EPI 6: plain bf16 store (QK projections)
          uint2 w2;
          w2.x = pkbf(acc[mi][ni][0], acc[mi][ni][1]);
          w2.y = pkbf(acc[mi][ni][2], acc[mi][ni][3]);
          *(uint2*)((u16*)Cp + (size_t)m * N + nb) = w2;
        }
      }
    }
  }
}

// ---------------- flash attention, causal, QBLK=128, swapped-QK^T --------
#define CEXP 0.18033688011112042f  /* log2(e)/8 */

__global__ __launch_bounds__(256, 3)
void attn_kernel(const u16* __restrict__ qkv, const u16* __restrict__ vT,
                 u16* __restrict__ ctx) {
  const int bh = blockIdx.x;
  const int qt = blockIdx.y;
  const int b = bh / NHEAD, h = bh % NHEAD;
  const int tid = threadIdx.x;
  const int wave = tid >> 6, lane = tid & 63;
  const int r = lane & 15, g = lane >> 4;

  __shared__ u16 Kb[2][64 * 64];
  __shared__ u16 Vb[2][64 * 64];
  __shared__ u16 Pt[4][16 * 64];

  const int qw = qt * 128 + wave * 32;
  const int tok0 = b * SEQ;

  short8 aq[2][2];
#pragma unroll
  for (int qf = 0; qf < 2; ++qf) {
    const u16* qb = qkv + (size_t)(tok0 + qw + qf * 16 + r) * QKVW + h * HD;
    aq[qf][0] = *(const short8*)(qb + g * 8);
    aq[qf][1] = *(const short8*)(qb + 32 + g * 8);
  }

  float l_st[2] = {0.f, 0.f};
  f32x4 oc[2][4] = {};

  const int sr = tid >> 3;
  const int sc = (tid & 7) * 8;
  const int nt = 2 * qt + 2;

  const u16* kg = qkv + (size_t)tok0 * QKVW + EMB + h * HD;
  const u16* vg = vT + (size_t)(h * HD) * NTOK + tok0;
  const int e0 = sc ^ ((sr & 7) << 3);

  auto stage = [&](int buf, int kt) {
    const size_t koff = (size_t)kt * 64;
    u16* kb = (u16*)Kb[buf] + wave * 512;
    u16* vb = (u16*)Vb[buf] + wave * 512;
    g2l16(kg + (koff + sr) * QKVW + e0, kb);
    g2l16(kg + (koff + sr + 32) * QKVW + e0, kb + 2048);
    g2l16(vg + (size_t)sr * NTOK + koff + e0, vb);
    g2l16(vg + (size_t)(sr + 32) * NTOK + koff + e0, vb + 2048);
  };

  stage(0, 0);
  for (int kb = 0; kb < nt; ++kb) {
    __syncthreads();
    const int cur = kb & 1;
    if (kb + 1 < nt) stage(cur ^ 1, kb + 1);

    const int kv0 = kb * 64;
    if (kv0 > qw + 31) continue;

    short8 kf[4][2];
#pragma unroll
    for (int nf = 0; nf < 4; ++nf) {
      const int row = nf * 16 + r;
#pragma unroll
      for (int kk = 0; kk < 2; ++kk)
        kf[nf][kk] = *(const short8*)((char*)Kb[cur] + row * 128 +
                                      ((kk * 64 + g * 16) ^ ((row & 7) << 4)));
    }
    short8 bv[2][4];
#pragma unroll
    for (int half = 0; half < 2; ++half)
#pragma unroll
      for (int nd = 0; nd < 4; ++nd) {
        const int vr = nd * 16 + r;
        bv[half][nd] = *(const short8*)((char*)Vb[cur] + vr * 128 +
                       ((half * 64 + g * 16) ^ ((vr & 7) << 4)));
      }

#pragma unroll
    for (int qf = 0; qf < 2; ++qf) {
      f32x4 st[4];
#pragma unroll
      for (int nf = 0; nf < 4; ++nf) {
        f32x4 z = {};
        z = __builtin_amdgcn_mfma_f32_16x16x32_bf16(kf[nf][0], aq[qf][0], z, 0, 0, 0);
        z = __builtin_amdgcn_mfma_f32_16x16x32_bf16(kf[nf][1], aq[qf][1], z, 0, 0, 0);
        st[nf] = z;
      }
      if (kv0 + 63 > qw + qf * 16) {
        const int qg = qw + qf * 16 + r;
#pragma unroll
        for (int nf = 0; nf < 4; ++nf)
#pragma unroll
          for (int j = 0; j < 4; ++j)
            if (kv0 + nf * 16 + 4 * g + j > qg) st[nf][j] = -3e38f;
      }
      float p[4][4];
      float ps = 0.f;
#pragma unroll
      for (int nf = 0; nf < 4; ++nf)
#pragma unroll
        for (int j = 0; j < 4; ++j) {
          const float pe = exp2f(st[nf][j] * CEXP);
          p[nf][j] = pe;
          ps += pe;
        }
      ps += __shfl_xor(ps, 16);
      ps += __shfl_xor(ps, 32);
      l_st[qf] += ps;

      u16* Pw = (u16*)Pt[wave];
#pragma unroll
      for (int nf = 0; nf < 4; ++nf) {
        uint2 w2;
        w2.x = pkbf(p[nf][0], p[nf][1]);
        w2.y = pkbf(p[nf][2], p[nf][3]);
        *(uint2*)((char*)Pw + r * 128 + ((nf * 32 + g * 8) ^ ((r & 7) << 4))) = w2;
      }
#pragma unroll
      for (int half = 0; half < 2; ++half) {
        short8 pa = *(const short8*)((char*)Pw + r * 128 +
                                     ((half * 64 + g * 16) ^ ((r & 7) << 4)));
#pragma unroll
        for (int nd = 0; nd < 4; ++nd)
          oc[qf][nd] = __builtin_amdgcn_mfma_f32_16x16x32_bf16(pa, bv[half][nd], oc[qf][nd], 0, 0, 0);
      }
    }
  }

#pragma unroll
  for (int qf = 0; qf < 2; ++qf) {
    const float rl = 1.f / l_st[qf];
#pragma unroll
    for (int j = 0; j < 4; ++j) {
      const float rj = __shfl(rl, 4 * g + j, 16);
      const size_t row = (size_t)tok0 + qw + qf * 16 + 4 * g + j;
#pragma unroll
      for (int nd = 0; nd < 4; ++nd)
        ctx[row * EMB + h * HD + nd * 16 + r] = f2bf(oc[qf][nd][j] * rj);
    }
  }
}

extern "C" void kernel_launch(void* const* d_in, const int* in_sizes, int n_in,
                              void* d_out, int out_size, void* d_ws, size_t ws_size,
                              hipStream_t stream) {
  const float* x    = (const float*)d_in[0];
  const float* Wq   = (const float*)d_in[1];
  const float* Wk   = (const float*)d_in[2];
  const float* Wv   = (const float*)d_in[3];
  const float* Wo   = (const float*)d_in[4];
  const float* bo   = (const float*)d_in[5];
  const float* W1   = (const float*)d_in[6];
  const float* b1   = (const float*)d_in[7];
  const float* W2   = (const float*)d_in[8];
  const float* b2   = (const float*)d_in[9];
  const float* ln1s = (const float*)d_in[10];
  const float* ln1b = (const float*)d_in[11];
  const float* ln2s = (const float*)d_in[12];
  const float* ln2b = (const float*)d_in[13];

  char* p = (char*)d_ws;
  u16* qkvT = (u16*)p; p += (size_t)QKVW * EMB * 2;
  u16* woT  = (u16*)p; p += (size_t)EMB * EMB * 2;
  u16* w1T  = (u16*)p; p += (size_t)FFD * EMB * 2;
  u16* w2T  = (u16*)p; p += (size_t)EMB * FFD * 2;
  u16* h1   = (u16*)p; p += (size_t)NTOK * EMB * 2;
  u16* qkv  = (u16*)p; p += (size_t)NTOK * QKVW * 2;
  u16* x2bf = (u16*)p; p += (size_t)NTOK * EMB * 2;
  u16* ff1  = (u16*)p; p += (size_t)NTOK * FFD * 2;
  u16* ctxb = h1;        // h1 dead after QKV GEMMs
  u16* h2   = qkv;       // qkv dead after attention
  u16* vT   = ff1;       // vT lives [V GEMM, attn); ff1 lives [FF1 GEMM, end)

  if (ws_size < (size_t)(p - (char*)d_ws)) return;

  dim3 blk(256);
  prep_kernel<<<8960, blk, 0, stream>>>(Wq, Wk, Wv, Wo, W1, W2, qkvT, woT, w1T, w2T,
                                        x, ln1s, ln1b, h1);
  // QK projections: SWAP mainloop, coalesced uint2 stores into qkv cols 0..1535
  gemm_kernel<6, 128, true><<<dim3(12, 64), blk, 0, stream>>>(
      h1, qkvT, qkv, nullptr, nullptr, nullptr, nullptr, NTOK, QKVW, EMB);
  // V projection: unswapped mainloop, transposed uint2 stores into vT[768][NTOK]
  gemm_kernel<7, 128, false><<<dim3(6, 64), blk, 0, stream>>>(
      h1, qkvT + (size_t)1536 * EMB, nullptr, nullptr, nullptr, nullptr, vT, NTOK, EMB, EMB);
  attn_kernel<<<dim3(96, 8), blk, 0, stream>>>(qkv, vT, ctxb);
  gemm_kernel<4, 64, true><<<dim3(6, 128), blk, 0, stream>>>(ctxb, woT, x2bf, bo, x, nullptr, nullptr, NTOK, EMB, EMB);
  ln_bf_vec_kernel<<<NTOK / 4, blk, 0, stream>>>(x2bf, ln2s, ln2b, h2);
  gemm_kernel<2, 128, true><<<dim3(24, 64), blk, 0, stream>>>(h2, w1T, ff1, b1, nullptr, nullptr, nullptr, NTOK, FFD, EMB);
  gemm_kernel<5, 64, true><<<dim3(6, 128), blk, 0, stream>>>(ff1, w2T, (float*)d_out, b2, nullptr, x2bf, nullptr, NTOK, EMB, FFD);
}

// Round 14
// 221.213 us; speedup vs baseline: 1.2665x; 1.0236x over previous
//
#include <hip/hip_runtime.h>
#include <hip/hip_bf16.h>
#include <stdint.h>
#include <stddef.h>

#define EMB 768
#define FFD 3072
#define NHEAD 12
#define HD 64
#define SEQ 1024
#define NTOK 8192
#define QKVW 2304

typedef unsigned short u16;
typedef __attribute__((ext_vector_type(8))) short short8;
typedef __attribute__((ext_vector_type(4))) float f32x4;

__device__ __forceinline__ u16 f2bf(float f) {
  union { float f; uint32_t u; } w; w.f = f;
  uint32_t x = w.u + 0x7fffu + ((w.u >> 16) & 1u);
  return (u16)(x >> 16);
}

__device__ __forceinline__ float bf2f(uint32_t v) {
  union { uint32_t u; float f; } c; c.u = v << 16; return c.f;
}

__device__ __forceinline__ uint32_t pkbf(float lo, float hi) {
  __hip_bfloat162 h = __float22bfloat162_rn(float2{lo, hi});
  union { __hip_bfloat162 h; uint32_t u; } cv; cv.h = h;
  return cv.u;
}

__device__ __forceinline__ void g2l16(const void* g, void* l) {
  __builtin_amdgcn_global_load_lds(
      (const __attribute__((address_space(1))) void*)g,
      (__attribute__((address_space(3))) void*)l, 16, 0, 0);
}

// ------------- prep kernel: 6 weight transposes + LN1, flat block decode ------
__global__ __launch_bounds__(256)
void prep_kernel(const float* __restrict__ Wq, const float* __restrict__ Wk,
                 const float* __restrict__ Wv, const float* __restrict__ Wo,
                 const float* __restrict__ W1, const float* __restrict__ W2,
                 u16* __restrict__ qkvT, u16* __restrict__ woT,
                 u16* __restrict__ w1T, u16* __restrict__ w2T,
                 const float* __restrict__ x, const float* __restrict__ sc,
                 const float* __restrict__ sh, u16* __restrict__ h1) {
  __shared__ float tile[32][33];
  const int id = blockIdx.x;
  if (id >= 6912) {
    const int wave = threadIdx.x >> 6, lane = threadIdx.x & 63;
    const int row = (id - 6912) * 4 + wave;
    const float* xr = x + (size_t)row * EMB;
    float4 v[3];
    float s = 0.f, ss = 0.f;
#pragma unroll
    for (int i = 0; i < 3; ++i) {
      v[i] = *(const float4*)(xr + lane * 4 + i * 256);
      s += v[i].x + v[i].y + v[i].z + v[i].w;
      ss += v[i].x * v[i].x + v[i].y * v[i].y + v[i].z * v[i].z + v[i].w * v[i].w;
    }
#pragma unroll
    for (int m = 1; m < 64; m <<= 1) { s += __shfl_xor(s, m, 64); ss += __shfl_xor(ss, m, 64); }
    const float mean = s * (1.f / EMB);
    const float inv = rsqrtf(ss * (1.f / EMB) - mean * mean + 1e-5f);
    u16* orow = h1 + (size_t)row * EMB;
#pragma unroll
    for (int i = 0; i < 3; ++i) {
      const int c = lane * 4 + i * 256;
      const float4 s4 = *(const float4*)(sc + c);
      const float4 h4 = *(const float4*)(sh + c);
      uint2 w2;
      w2.x = pkbf((v[i].x - mean) * inv * s4.x + h4.x, (v[i].y - mean) * inv * s4.y + h4.y);
      w2.y = pkbf((v[i].z - mean) * inv * s4.z + h4.z, (v[i].w - mean) * inv * s4.w + h4.w);
      *(uint2*)(orow + c) = w2;
    }
    return;
  }
  const float* in; u16* out; int K, N, bx, by;
  if (id < 1728) {
    const int z = id / 576, rem = id % 576;
    in = z == 0 ? Wq : (z == 1 ? Wk : Wv);
    out = qkvT + (size_t)z * EMB * EMB;
    K = EMB; N = EMB; bx = rem % 24; by = rem / 24;
  } else if (id < 2304) {
    const int rem = id - 1728;
    in = Wo; out = woT; K = EMB; N = EMB; bx = rem % 24; by = rem / 24;
  } else if (id < 4608) {
    const int rem = id - 2304;
    in = W1; out = w1T; K = EMB; N = FFD; bx = rem % 96; by = rem / 96;
  } else {
    const int rem = id - 4608;
    in = W2; out = w2T; K = FFD; N = EMB; bx = rem % 24; by = rem / 24;
  }
  const int n0 = bx * 32, k0 = by * 32;
  const int tx = threadIdx.x & 31;
  const int ty = threadIdx.x >> 5;
#pragma unroll
  for (int i = 0; i < 32; i += 8)
    tile[ty + i][tx] = in[(size_t)(k0 + ty + i) * N + n0 + tx];
  __syncthreads();
#pragma unroll
  for (int i = 0; i < 32; i += 8)
    out[(size_t)(n0 + ty + i) * K + k0 + tx] = f2bf(tile[tx][ty + i]);
}

// layernorm, wave-per-row, vectorized (bf16 in)
__global__ __launch_bounds__(256)
void ln_bf_vec_kernel(const u16* __restrict__ x, const float* __restrict__ sc,
                      const float* __restrict__ sh, u16* __restrict__ out) {
  const int wave = threadIdx.x >> 6, lane = threadIdx.x & 63;
  const int row = blockIdx.x * 4 + wave;
  const u16* xr = x + (size_t)row * EMB;
  float v[3][4];
  float s = 0.f, ss = 0.f;
#pragma unroll
  for (int i = 0; i < 3; ++i) {
    const uint2 r2 = *(const uint2*)(xr + lane * 4 + i * 256);
    v[i][0] = bf2f(r2.x & 0xffffu);
    v[i][1] = bf2f(r2.x >> 16);
    v[i][2] = bf2f(r2.y & 0xffffu);
    v[i][3] = bf2f(r2.y >> 16);
#pragma unroll
    for (int j = 0; j < 4; ++j) { s += v[i][j]; ss += v[i][j] * v[i][j]; }
  }
#pragma unroll
  for (int m = 1; m < 64; m <<= 1) { s += __shfl_xor(s, m, 64); ss += __shfl_xor(ss, m, 64); }
  const float mean = s * (1.f / EMB);
  const float inv = rsqrtf(ss * (1.f / EMB) - mean * mean + 1e-5f);
  u16* orow = out + (size_t)row * EMB;
#pragma unroll
  for (int i = 0; i < 3; ++i) {
    const int c = lane * 4 + i * 256;
    const float4 s4 = *(const float4*)(sc + c);
    const float4 h4 = *(const float4*)(sh + c);
    uint2 w2;
    w2.x = pkbf((v[i][0] - mean) * inv * s4.x + h4.x, (v[i][1] - mean) * inv * s4.y + h4.y);
    w2.y = pkbf((v[i][2] - mean) * inv * s4.z + h4.z, (v[i][3] - mean) * inv * s4.w + h4.w);
    *(uint2*)(orow + c) = w2;
  }
}

// ---------------- bf16 GEMM: C[M,N] = A[M,K] @ BT[N,K]^T ----------------
// r10 mainloop, verbatim structure (single-buffered, 16x16x32, BK=64,
// conflict-free XOR swizzle, row-major XCD swizzle).  ONE change vs r10:
// M/N/K are template constants -> all stride math strength-reduces to
// shifts/adds and the K-loop fully unrolls (VALU addr-calc reduction).
// SWAP=true: mfma(bf, af) -> lane holds one M-row, 4 consecutive N-cols.
// EPI 2 (SWAP): C bf16 = gelu_tanh(acc + bias[n])          (uint2 st)
// EPI 4 (SWAP): C bf16 = acc + bias[n] + resf32[m*N+n]     (uint2 st)
// EPI 5 (SWAP): C f32  = acc + bias[n] + bf2f(res16[...])  (float4 st)
// EPI 3 (!SWAP): QKV split (cols<1536 row-major bf16; V cols -> vTp transposed)
template <int EPI, int MT, bool SWAP, int M, int N, int K>
__global__ __launch_bounds__(256)
void gemm_kernel(const u16* __restrict__ A, const u16* __restrict__ BT,
                 void* __restrict__ Cp, const float* __restrict__ bias,
                 const float* __restrict__ res, const u16* __restrict__ res16,
                 u16* __restrict__ vTp) {
  constexpr int MI = MT / 32;
  constexpr int GX = N / 128;
  constexpr int NWG = GX * (M / MT);
  __shared__ u16 As[MT * 64];
  __shared__ u16 Bs[128 * 64];

  const int orig = blockIdx.y * GX + blockIdx.x;
  const int swz = (orig & 7) * (NWG >> 3) + (orig >> 3);
  const int m0 = (swz / GX) * MT;
  const int n0 = (swz % GX) * 128;

  const int tid = threadIdx.x;
  const int wave = tid >> 6, lane = tid & 63;
  const int wr = wave >> 1, wc = wave & 1;
  const int r = lane & 15, g = lane >> 4;
  const int lrow = lane >> 3;
  const int lelem = (lane & 7) * 8;

  f32x4 acc[MI][4] = {};

  constexpr int NKT = K / 64;
  for (int kt = 0; kt < NKT; ++kt) {
    const int k0 = kt << 6;
    if (kt) __syncthreads();
#pragma unroll
    for (int q = 0; q < MT / 32; ++q) {
      const int chunk = q * 4 + wave;
      const int row = chunk * 8 + lrow;
      const int e = lelem ^ ((row & 7) << 3);
      g2l16(A + (size_t)(m0 + row) * K + k0 + e, As + chunk * 512);
    }
#pragma unroll
    for (int q = 0; q < 4; ++q) {
      const int chunk = q * 4 + wave;
      const int row = chunk * 8 + lrow;
      const int e = lelem ^ ((row & 7) << 3);
      g2l16(BT + (size_t)(n0 + row) * K + k0 + e, Bs + chunk * 512);
    }
    __syncthreads();
#pragma unroll
    for (int kk = 0; kk < 2; ++kk) {
      short8 af[MI], bf[4];
#pragma unroll
      for (int mi = 0; mi < MI; ++mi) {
        const int row = wr * (MT / 2) + mi * 16 + r;
        af[mi] = *(const short8*)(As + row * 64 + ((kk * 32 + g * 8) ^ ((row & 7) << 3)));
      }
#pragma unroll
      for (int ni = 0; ni < 4; ++ni) {
        const int row = wc * 64 + ni * 16 + r;
        bf[ni] = *(const short8*)(Bs + row * 64 + ((kk * 32 + g * 8) ^ ((row & 7) << 3)));
      }
#pragma unroll
      for (int mi = 0; mi < MI; ++mi)
#pragma unroll
        for (int ni = 0; ni < 4; ++ni) {
          if constexpr (SWAP)
            acc[mi][ni] = __builtin_amdgcn_mfma_f32_16x16x32_bf16(bf[ni], af[mi], acc[mi][ni], 0, 0, 0);
          else
            acc[mi][ni] = __builtin_amdgcn_mfma_f32_16x16x32_bf16(af[mi], bf[ni], acc[mi][ni], 0, 0, 0);
        }
    }
  }

  if constexpr (!SWAP) {
    // EPI 3: lane owns col = n0+wc*64+ni*16+r (fixed), rows rowb+0..3
#pragma unroll
    for (int mi = 0; mi < MI; ++mi)
#pragma unroll
      for (int ni = 0; ni < 4; ++ni) {
        const int rowb = m0 + wr * (MT / 2) + mi * 16 + 4 * g;
        const int col = n0 + wc * 64 + ni * 16 + r;
        u16 pk[4];
#pragma unroll
        for (int j = 0; j < 4; ++j) pk[j] = f2bf(acc[mi][ni][j]);
        if (col < 1536) {
#pragma unroll
          for (int j = 0; j < 4; ++j)
            ((u16*)Cp)[(size_t)(rowb + j) * N + col] = pk[j];
        } else {
          uint2 w2;
          w2.x = (uint32_t)pk[0] | ((uint32_t)pk[1] << 16);
          w2.y = (uint32_t)pk[2] | ((uint32_t)pk[3] << 16);
          *(uint2*)(vTp + (size_t)(col - 1536) * NTOK + rowb) = w2;
        }
      }
  } else {
    // SWAP epilogue: lane owns m (fixed), 4 consecutive cols nb..nb+3
#pragma unroll
    for (int mi = 0; mi < MI; ++mi) {
      const int m = m0 + wr * (MT / 2) + mi * 16 + r;
#pragma unroll
      for (int ni = 0; ni < 4; ++ni) {
        const int nb = n0 + wc * 64 + ni * 16 + 4 * g;
        if constexpr (EPI == 2) {
          const float4 bs = *(const float4*)(bias + nb);
          float tj[4];
#pragma unroll
          for (int j = 0; j < 4; ++j) {
            float t = acc[mi][ni][j] + (&bs.x)[j];
            float e = __expf(1.5957691216057308f * (t + 0.044715f * t * t * t));
            tj[j] = 0.5f * t * (1.f + (1.f - 2.f / (e + 1.f)));
          }
          uint2 w2;
          w2.x = pkbf(tj[0], tj[1]);
          w2.y = pkbf(tj[2], tj[3]);
          *(uint2*)((u16*)Cp + (size_t)m * N + nb) = w2;
        } else if constexpr (EPI == 4) {
          const float4 bs = *(const float4*)(bias + nb);
          const float4 rs = *(const float4*)(res + (size_t)m * N + nb);
          uint2 w2;
          w2.x = pkbf(acc[mi][ni][0] + bs.x + rs.x, acc[mi][ni][1] + bs.y + rs.y);
          w2.y = pkbf(acc[mi][ni][2] + bs.z + rs.z, acc[mi][ni][3] + bs.w + rs.w);
          *(uint2*)((u16*)Cp + (size_t)m * N + nb) = w2;
        } else {  // EPI 5
          const float4 bs = *(const float4*)(bias + nb);
          const uint2 r2 = *(const uint2*)(res16 + (size_t)m * N + nb);
          float4 o;
          o.x = acc[mi][ni][0] + bs.x + bf2f(r2.x & 0xffffu);
          o.y = acc[mi][ni][1] + bs.y + bf2f(r2.x >> 16);
          o.z = acc[mi][ni][2] + bs.z + bf2f(r2.y & 0xffffu);
          o.w = acc[mi][ni][3] + bs.w + bf2f(r2.y >> 16);
          *(float4*)((float*)Cp + (size_t)m * N + nb) = o;
        }
      }
    }
  }
}

// ---------------- flash attention, causal, QBLK=128, swapped-QK^T --------
#define CEXP 0.18033688011112042f  /* log2(e)/8 */

__global__ __launch_bounds__(256, 3)
void attn_kernel(const u16* __restrict__ qkv, const u16* __restrict__ vT,
                 u16* __restrict__ ctx) {
  const int bh = blockIdx.x;
  const int qt = blockIdx.y;
  const int b = bh / NHEAD, h = bh % NHEAD;
  const int tid = threadIdx.x;
  const int wave = tid >> 6, lane = tid & 63;
  const int r = lane & 15, g = lane >> 4;

  __shared__ u16 Kb[2][64 * 64];
  __shared__ u16 Vb[2][64 * 64];
  __shared__ u16 Pt[4][16 * 64];

  const int qw = qt * 128 + wave * 32;
  const int tok0 = b * SEQ;

  short8 aq[2][2];
#pragma unroll
  for (int qf = 0; qf < 2; ++qf) {
    const u16* qb = qkv + (size_t)(tok0 + qw + qf * 16 + r) * QKVW + h * HD;
    aq[qf][0] = *(const short8*)(qb + g * 8);
    aq[qf][1] = *(const short8*)(qb + 32 + g * 8);
  }

  float l_st[2] = {0.f, 0.f};
  f32x4 oc[2][4] = {};

  const int sr = tid >> 3;
  const int sc = (tid & 7) * 8;
  const int nt = 2 * qt + 2;

  const u16* kg = qkv + (size_t)tok0 * QKVW + EMB + h * HD;
  const u16* vg = vT + (size_t)(h * HD) * NTOK + tok0;
  const int e0 = sc ^ ((sr & 7) << 3);

  auto stage = [&](int buf, int kt) {
    const size_t koff = (size_t)kt * 64;
    u16* kb = (u16*)Kb[buf] + wave * 512;
    u16* vb = (u16*)Vb[buf] + wave * 512;
    g2l16(kg + (koff + sr) * QKVW + e0, kb);
    g2l16(kg + (koff + sr + 32) * QKVW + e0, kb + 2048);
    g2l16(vg + (size_t)sr * NTOK + koff + e0, vb);
    g2l16(vg + (size_t)(sr + 32) * NTOK + koff + e0, vb + 2048);
  };

  stage(0, 0);
  for (int kb = 0; kb < nt; ++kb) {
    __syncthreads();
    const int cur = kb & 1;
    if (kb + 1 < nt) stage(cur ^ 1, kb + 1);

    const int kv0 = kb * 64;
    if (kv0 > qw + 31) continue;

    short8 kf[4][2];
#pragma unroll
    for (int nf = 0; nf < 4; ++nf) {
      const int row = nf * 16 + r;
#pragma unroll
      for (int kk = 0; kk < 2; ++kk)
        kf[nf][kk] = *(const short8*)((char*)Kb[cur] + row * 128 +
                                      ((kk * 64 + g * 16) ^ ((row & 7) << 4)));
    }
    short8 bv[2][4];
#pragma unroll
    for (int half = 0; half < 2; ++half)
#pragma unroll
      for (int nd = 0; nd < 4; ++nd) {
        const int vr = nd * 16 + r;
        bv[half][nd] = *(const short8*)((char*)Vb[cur] + vr * 128 +
                       ((half * 64 + g * 16) ^ ((vr & 7) << 4)));
      }

#pragma unroll
    for (int qf = 0; qf < 2; ++qf) {
      f32x4 st[4];
#pragma unroll
      for (int nf = 0; nf < 4; ++nf) {
        f32x4 z = {};
        z = __builtin_amdgcn_mfma_f32_16x16x32_bf16(kf[nf][0], aq[qf][0], z, 0, 0, 0);
        z = __builtin_amdgcn_mfma_f32_16x16x32_bf16(kf[nf][1], aq[qf][1], z, 0, 0, 0);
        st[nf] = z;
      }
      if (kv0 + 63 > qw + qf * 16) {
        const int qg = qw + qf * 16 + r;
#pragma unroll
        for (int nf = 0; nf < 4; ++nf)
#pragma unroll
          for (int j = 0; j < 4; ++j)
            if (kv0 + nf * 16 + 4 * g + j > qg) st[nf][j] = -3e38f;
      }
      float p[4][4];
      float ps = 0.f;
#pragma unroll
      for (int nf = 0; nf < 4; ++nf)
#pragma unroll
        for (int j = 0; j < 4; ++j) {
          const float pe = exp2f(st[nf][j] * CEXP);
          p[nf][j] = pe;
          ps += pe;
        }
      ps += __shfl_xor(ps, 16);
      ps += __shfl_xor(ps, 32);
      l_st[qf] += ps;

      u16* Pw = (u16*)Pt[wave];
#pragma unroll
      for (int nf = 0; nf < 4; ++nf) {
        uint2 w2;
        w2.x = pkbf(p[nf][0], p[nf][1]);
        w2.y = pkbf(p[nf][2], p[nf][3]);
        *(uint2*)((char*)Pw + r * 128 + ((nf * 32 + g * 8) ^ ((r & 7) << 4))) = w2;
      }
#pragma unroll
      for (int half = 0; half < 2; ++half) {
        short8 pa = *(const short8*)((char*)Pw + r * 128 +
                                     ((half * 64 + g * 16) ^ ((r & 7) << 4)));
#pragma unroll
        for (int nd = 0; nd < 4; ++nd)
          oc[qf][nd] = __builtin_amdgcn_mfma_f32_16x16x32_bf16(pa, bv[half][nd], oc[qf][nd], 0, 0, 0);
      }
    }
  }

#pragma unroll
  for (int qf = 0; qf < 2; ++qf) {
    const float rl = 1.f / l_st[qf];
#pragma unroll
    for (int j = 0; j < 4; ++j) {
      const float rj = __shfl(rl, 4 * g + j, 16);
      const size_t row = (size_t)tok0 + qw + qf * 16 + 4 * g + j;
#pragma unroll
      for (int nd = 0; nd < 4; ++nd)
        ctx[row * EMB + h * HD + nd * 16 + r] = f2bf(oc[qf][nd][j] * rj);
    }
  }
}

extern "C" void kernel_launch(void* const* d_in, const int* in_sizes, int n_in,
                              void* d_out, int out_size, void* d_ws, size_t ws_size,
                              hipStream_t stream) {
  const float* x    = (const float*)d_in[0];
  const float* Wq   = (const float*)d_in[1];
  const float* Wk   = (const float*)d_in[2];
  const float* Wv   = (const float*)d_in[3];
  const float* Wo   = (const float*)d_in[4];
  const float* bo   = (const float*)d_in[5];
  const float* W1   = (const float*)d_in[6];
  const float* b1   = (const float*)d_in[7];
  const float* W2   = (const float*)d_in[8];
  const float* b2   = (const float*)d_in[9];
  const float* ln1s = (const float*)d_in[10];
  const float* ln1b = (const float*)d_in[11];
  const float* ln2s = (const float*)d_in[12];
  const float* ln2b = (const float*)d_in[13];

  char* p = (char*)d_ws;
  u16* qkvT = (u16*)p; p += (size_t)QKVW * EMB * 2;
  u16* woT  = (u16*)p; p += (size_t)EMB * EMB * 2;
  u16* w1T  = (u16*)p; p += (size_t)FFD * EMB * 2;
  u16* w2T  = (u16*)p; p += (size_t)EMB * FFD * 2;
  u16* h1   = (u16*)p; p += (size_t)NTOK * EMB * 2;
  u16* qkv  = (u16*)p; p += (size_t)NTOK * QKVW * 2;
  u16* x2bf = (u16*)p; p += (size_t)NTOK * EMB * 2;
  u16* ff1  = (u16*)p; p += (size_t)NTOK * FFD * 2;
  u16* ctxb = h1;        // h1 dead after QKV GEMM
  u16* h2   = qkv;       // qkv dead after attention
  u16* vT   = ff1;       // vT lives [QKV GEMM, attn); ff1 lives [FF1 GEMM, end)

  if (ws_size < (size_t)(p - (char*)d_ws)) return;

  dim3 blk(256);
  prep_kernel<<<8960, blk, 0, stream>>>(Wq, Wk, Wv, Wo, W1, W2, qkvT, woT, w1T, w2T,
                                        x, ln1s, ln1b, h1);
  gemm_kernel<3, 128, false, NTOK, QKVW, EMB><<<dim3(18, 64), blk, 0, stream>>>(
      h1, qkvT, qkv, nullptr, nullptr, nullptr, vT);
  attn_kernel<<<dim3(96, 8), blk, 0, stream>>>(qkv, vT, ctxb);
  gemm_kernel<4, 64, true, NTOK, EMB, EMB><<<dim3(6, 128), blk, 0, stream>>>(
      ctxb, woT, x2bf, bo, x, nullptr, nullptr);
  ln_bf_vec_kernel<<<NTOK / 4, blk, 0, stream>>>(x2bf, ln2s, ln2b, h2);
  gemm_kernel<2, 128, true, NTOK, FFD, EMB><<<dim3(24, 64), blk, 0, stream>>>(
      h2, w1T, ff1, b1, nullptr, nullptr, nullptr);
  gemm_kernel<5, 64, true, NTOK, EMB, FFD><<<dim3(6, 128), blk, 0, stream>>>(
      ff1, w2T, (float*)d_out, b2, nullptr, x2bf, nullptr);
}

// Round 15
// 219.747 us; speedup vs baseline: 1.2749x; 1.0067x over previous
//
#include <hip/hip_runtime.h>
#include <hip/hip_bf16.h>
#include <stdint.h>
#include <stddef.h>

#define EMB 768
#define FFD 3072
#define NHEAD 12
#define HD 64
#define SEQ 1024
#define NTOK 8192
#define QKVW 2304

typedef unsigned short u16;
typedef __attribute__((ext_vector_type(8))) short short8;
typedef __attribute__((ext_vector_type(4))) float f32x4;

__device__ __forceinline__ u16 f2bf(float f) {
  union { float f; uint32_t u; } w; w.f = f;
  uint32_t x = w.u + 0x7fffu + ((w.u >> 16) & 1u);
  return (u16)(x >> 16);
}

__device__ __forceinline__ float bf2f(uint32_t v) {
  union { uint32_t u; float f; } c; c.u = v << 16; return c.f;
}

__device__ __forceinline__ uint32_t pkbf(float lo, float hi) {
  __hip_bfloat162 h = __float22bfloat162_rn(float2{lo, hi});
  union { __hip_bfloat162 h; uint32_t u; } cv; cv.h = h;
  return cv.u;
}

__device__ __forceinline__ void g2l16(const void* g, void* l) {
  __builtin_amdgcn_global_load_lds(
      (const __attribute__((address_space(1))) void*)g,
      (__attribute__((address_space(3))) void*)l, 16, 0, 0);
}

// ------------- prep kernel: 6 weight transposes + LN1, flat block decode ------
__global__ __launch_bounds__(256)
void prep_kernel(const float* __restrict__ Wq, const float* __restrict__ Wk,
                 const float* __restrict__ Wv, const float* __restrict__ Wo,
                 const float* __restrict__ W1, const float* __restrict__ W2,
                 u16* __restrict__ qkvT, u16* __restrict__ woT,
                 u16* __restrict__ w1T, u16* __restrict__ w2T,
                 const float* __restrict__ x, const float* __restrict__ sc,
                 const float* __restrict__ sh, u16* __restrict__ h1) {
  __shared__ float tile[32][33];
  const int id = blockIdx.x;
  if (id >= 6912) {
    const int wave = threadIdx.x >> 6, lane = threadIdx.x & 63;
    const int row = (id - 6912) * 4 + wave;
    const float* xr = x + (size_t)row * EMB;
    float4 v[3];
    float s = 0.f, ss = 0.f;
#pragma unroll
    for (int i = 0; i < 3; ++i) {
      v[i] = *(const float4*)(xr + lane * 4 + i * 256);
      s += v[i].x + v[i].y + v[i].z + v[i].w;
      ss += v[i].x * v[i].x + v[i].y * v[i].y + v[i].z * v[i].z + v[i].w * v[i].w;
    }
#pragma unroll
    for (int m = 1; m < 64; m <<= 1) { s += __shfl_xor(s, m, 64); ss += __shfl_xor(ss, m, 64); }
    const float mean = s * (1.f / EMB);
    const float inv = rsqrtf(ss * (1.f / EMB) - mean * mean + 1e-5f);
    u16* orow = h1 + (size_t)row * EMB;
#pragma unroll
    for (int i = 0; i < 3; ++i) {
      const int c = lane * 4 + i * 256;
      const float4 s4 = *(const float4*)(sc + c);
      const float4 h4 = *(const float4*)(sh + c);
      uint2 w2;
      w2.x = pkbf((v[i].x - mean) * inv * s4.x + h4.x, (v[i].y - mean) * inv * s4.y + h4.y);
      w2.y = pkbf((v[i].z - mean) * inv * s4.z + h4.z, (v[i].w - mean) * inv * s4.w + h4.w);
      *(uint2*)(orow + c) = w2;
    }
    return;
  }
  const float* in; u16* out; int K, N, bx, by;
  if (id < 1728) {
    const int z = id / 576, rem = id % 576;
    in = z == 0 ? Wq : (z == 1 ? Wk : Wv);
    out = qkvT + (size_t)z * EMB * EMB;
    K = EMB; N = EMB; bx = rem % 24; by = rem / 24;
  } else if (id < 2304) {
    const int rem = id - 1728;
    in = Wo; out = woT; K = EMB; N = EMB; bx = rem % 24; by = rem / 24;
  } else if (id < 4608) {
    const int rem = id - 2304;
    in = W1; out = w1T; K = EMB; N = FFD; bx = rem % 96; by = rem / 96;
  } else {
    const int rem = id - 4608;
    in = W2; out = w2T; K = FFD; N = EMB; bx = rem % 24; by = rem / 24;
  }
  const int n0 = bx * 32, k0 = by * 32;
  const int tx = threadIdx.x & 31;
  const int ty = threadIdx.x >> 5;
#pragma unroll
  for (int i = 0; i < 32; i += 8)
    tile[ty + i][tx] = in[(size_t)(k0 + ty + i) * N + n0 + tx];
  __syncthreads();
#pragma unroll
  for (int i = 0; i < 32; i += 8)
    out[(size_t)(n0 + ty + i) * K + k0 + tx] = f2bf(tile[tx][ty + i]);
}

// layernorm, wave-per-row, vectorized (bf16 in)
__global__ __launch_bounds__(256)
void ln_bf_vec_kernel(const u16* __restrict__ x, const float* __restrict__ sc,
                      const float* __restrict__ sh, u16* __restrict__ out) {
  const int wave = threadIdx.x >> 6, lane = threadIdx.x & 63;
  const int row = blockIdx.x * 4 + wave;
  const u16* xr = x + (size_t)row * EMB;
  float v[3][4];
  float s = 0.f, ss = 0.f;
#pragma unroll
  for (int i = 0; i < 3; ++i) {
    const uint2 r2 = *(const uint2*)(xr + lane * 4 + i * 256);
    v[i][0] = bf2f(r2.x & 0xffffu);
    v[i][1] = bf2f(r2.x >> 16);
    v[i][2] = bf2f(r2.y & 0xffffu);
    v[i][3] = bf2f(r2.y >> 16);
#pragma unroll
    for (int j = 0; j < 4; ++j) { s += v[i][j]; ss += v[i][j] * v[i][j]; }
  }
#pragma unroll
  for (int m = 1; m < 64; m <<= 1) { s += __shfl_xor(s, m, 64); ss += __shfl_xor(ss, m, 64); }
  const float mean = s * (1.f / EMB);
  const float inv = rsqrtf(ss * (1.f / EMB) - mean * mean + 1e-5f);
  u16* orow = out + (size_t)row * EMB;
#pragma unroll
  for (int i = 0; i < 3; ++i) {
    const int c = lane * 4 + i * 256;
    const float4 s4 = *(const float4*)(sc + c);
    const float4 h4 = *(const float4*)(sh + c);
    uint2 w2;
    w2.x = pkbf((v[i][0] - mean) * inv * s4.x + h4.x, (v[i][1] - mean) * inv * s4.y + h4.y);
    w2.y = pkbf((v[i][2] - mean) * inv * s4.z + h4.z, (v[i][3] - mean) * inv * s4.w + h4.w);
    *(uint2*)(orow + c) = w2;
  }
}

// ---------------- bf16 GEMM: C[M,N] = A[M,K] @ BT[N,K]^T ----------------
// r14 mainloop verbatim.  NEW: GM x GN super-tile decode after the XCD swizzle
// (GM=1, GN=GX is the identity == r14's row-major).  For FF1 (B=4.7MB > 4MB L2)
// GM=4 x GN=12 keeps each XCD's 2.4MB B-chunk L2-resident across its whole
// chunk -> B re-reads become L2 hits instead of L3 round-trips.
// SWAP=true: mfma(bf, af) -> lane holds one M-row, 4 consecutive N-cols.
// EPI 2 (SWAP): C bf16 = gelu_tanh(acc + bias[n])          (uint2 st)
// EPI 4 (SWAP): C bf16 = acc + bias[n] + resf32[m*N+n]     (uint2 st)
// EPI 5 (SWAP): C f32  = acc + bias[n] + bf2f(res16[...])  (float4 st)
// EPI 3 (!SWAP): QKV split (cols<1536 row-major bf16; V cols -> vTp transposed)
template <int EPI, int MT, bool SWAP, int M, int N, int K, int GM, int GN>
__global__ __launch_bounds__(256)
void gemm_kernel(const u16* __restrict__ A, const u16* __restrict__ BT,
                 void* __restrict__ Cp, const float* __restrict__ bias,
                 const float* __restrict__ res, const u16* __restrict__ res16,
                 u16* __restrict__ vTp) {
  constexpr int MI = MT / 32;
  constexpr int GX = N / 128;
  constexpr int MB_ = M / MT;
  constexpr int NWG = GX * MB_;
  static_assert(MB_ % GM == 0 && GX % GN == 0, "group decode");
  __shared__ u16 As[MT * 64];
  __shared__ u16 Bs[128 * 64];

  const int orig = blockIdx.y * GX + blockIdx.x;
  const int swz = (orig & 7) * (NWG >> 3) + (orig >> 3);
  // super-tile decode: supers walk m-first, so consecutive swz share a B-chunk
  constexpr int SUP = GM * GN;
  constexpr int SPM = MB_ / GM;
  const int sup = swz / SUP;
  const int loc = swz % SUP;
  const int m0 = ((sup % SPM) * GM + (loc % GM)) * MT;
  const int n0 = ((sup / SPM) * GN + (loc / GM)) * 128;

  const int tid = threadIdx.x;
  const int wave = tid >> 6, lane = tid & 63;
  const int wr = wave >> 1, wc = wave & 1;
  const int r = lane & 15, g = lane >> 4;
  const int lrow = lane >> 3;
  const int lelem = (lane & 7) * 8;

  f32x4 acc[MI][4] = {};

  constexpr int NKT = K / 64;
  for (int kt = 0; kt < NKT; ++kt) {
    const int k0 = kt << 6;
    if (kt) __syncthreads();
#pragma unroll
    for (int q = 0; q < MT / 32; ++q) {
      const int chunk = q * 4 + wave;
      const int row = chunk * 8 + lrow;
      const int e = lelem ^ ((row & 7) << 3);
      g2l16(A + (size_t)(m0 + row) * K + k0 + e, As + chunk * 512);
    }
#pragma unroll
    for (int q = 0; q < 4; ++q) {
      const int chunk = q * 4 + wave;
      const int row = chunk * 8 + lrow;
      const int e = lelem ^ ((row & 7) << 3);
      g2l16(BT + (size_t)(n0 + row) * K + k0 + e, Bs + chunk * 512);
    }
    __syncthreads();
#pragma unroll
    for (int kk = 0; kk < 2; ++kk) {
      short8 af[MI], bf[4];
#pragma unroll
      for (int mi = 0; mi < MI; ++mi) {
        const int row = wr * (MT / 2) + mi * 16 + r;
        af[mi] = *(const short8*)(As + row * 64 + ((kk * 32 + g * 8) ^ ((row & 7) << 3)));
      }
#pragma unroll
      for (int ni = 0; ni < 4; ++ni) {
        const int row = wc * 64 + ni * 16 + r;
        bf[ni] = *(const short8*)(Bs + row * 64 + ((kk * 32 + g * 8) ^ ((row & 7) << 3)));
      }
#pragma unroll
      for (int mi = 0; mi < MI; ++mi)
#pragma unroll
        for (int ni = 0; ni < 4; ++ni) {
          if constexpr (SWAP)
            acc[mi][ni] = __builtin_amdgcn_mfma_f32_16x16x32_bf16(bf[ni], af[mi], acc[mi][ni], 0, 0, 0);
          else
            acc[mi][ni] = __builtin_amdgcn_mfma_f32_16x16x32_bf16(af[mi], bf[ni], acc[mi][ni], 0, 0, 0);
        }
    }
  }

  if constexpr (!SWAP) {
    // EPI 3: lane owns col = n0+wc*64+ni*16+r (fixed), rows rowb+0..3
#pragma unroll
    for (int mi = 0; mi < MI; ++mi)
#pragma unroll
      for (int ni = 0; ni < 4; ++ni) {
        const int rowb = m0 + wr * (MT / 2) + mi * 16 + 4 * g;
        const int col = n0 + wc * 64 + ni * 16 + r;
        u16 pk[4];
#pragma unroll
        for (int j = 0; j < 4; ++j) pk[j] = f2bf(acc[mi][ni][j]);
        if (col < 1536) {
#pragma unroll
          for (int j = 0; j < 4; ++j)
            ((u16*)Cp)[(size_t)(rowb + j) * N + col] = pk[j];
        } else {
          uint2 w2;
          w2.x = (uint32_t)pk[0] | ((uint32_t)pk[1] << 16);
          w2.y = (uint32_t)pk[2] | ((uint32_t)pk[3] << 16);
          *(uint2*)(vTp + (size_t)(col - 1536) * NTOK + rowb) = w2;
        }
      }
  } else {
    // SWAP epilogue: lane owns m (fixed), 4 consecutive cols nb..nb+3
#pragma unroll
    for (int mi = 0; mi < MI; ++mi) {
      const int m = m0 + wr * (MT / 2) + mi * 16 + r;
#pragma unroll
      for (int ni = 0; ni < 4; ++ni) {
        const int nb = n0 + wc * 64 + ni * 16 + 4 * g;
        if constexpr (EPI == 2) {
          const float4 bs = *(const float4*)(bias + nb);
          float tj[4];
#pragma unroll
          for (int j = 0; j < 4; ++j) {
            float t = acc[mi][ni][j] + (&bs.x)[j];
            float e = __expf(1.5957691216057308f * (t + 0.044715f * t * t * t));
            tj[j] = 0.5f * t * (1.f + (1.f - 2.f / (e + 1.f)));
          }
          uint2 w2;
          w2.x = pkbf(tj[0], tj[1]);
          w2.y = pkbf(tj[2], tj[3]);
          *(uint2*)((u16*)Cp + (size_t)m * N + nb) = w2;
        } else if constexpr (EPI == 4) {
          const float4 bs = *(const float4*)(bias + nb);
          const float4 rs = *(const float4*)(res + (size_t)m * N + nb);
          uint2 w2;
          w2.x = pkbf(acc[mi][ni][0] + bs.x + rs.x, acc[mi][ni][1] + bs.y + rs.y);
          w2.y = pkbf(acc[mi][ni][2] + bs.z + rs.z, acc[mi][ni][3] + bs.w + rs.w);
          *(uint2*)((u16*)Cp + (size_t)m * N + nb) = w2;
        } else {  // EPI 5
          const float4 bs = *(const float4*)(bias + nb);
          const uint2 r2 = *(const uint2*)(res16 + (size_t)m * N + nb);
          float4 o;
          o.x = acc[mi][ni][0] + bs.x + bf2f(r2.x & 0xffffu);
          o.y = acc[mi][ni][1] + bs.y + bf2f(r2.x >> 16);
          o.z = acc[mi][ni][2] + bs.z + bf2f(r2.y & 0xffffu);
          o.w = acc[mi][ni][3] + bs.w + bf2f(r2.y >> 16);
          *(float4*)((float*)Cp + (size_t)m * N + nb) = o;
        }
      }
    }
  }
}

// ---------------- flash attention, causal, QBLK=128, swapped-QK^T --------
#define CEXP 0.18033688011112042f  /* log2(e)/8 */

__global__ __launch_bounds__(256, 3)
void attn_kernel(const u16* __restrict__ qkv, const u16* __restrict__ vT,
                 u16* __restrict__ ctx) {
  const int bh = blockIdx.x;
  const int qt = blockIdx.y;
  const int b = bh / NHEAD, h = bh % NHEAD;
  const int tid = threadIdx.x;
  const int wave = tid >> 6, lane = tid & 63;
  const int r = lane & 15, g = lane >> 4;

  __shared__ u16 Kb[2][64 * 64];
  __shared__ u16 Vb[2][64 * 64];
  __shared__ u16 Pt[4][16 * 64];

  const int qw = qt * 128 + wave * 32;
  const int tok0 = b * SEQ;

  short8 aq[2][2];
#pragma unroll
  for (int qf = 0; qf < 2; ++qf) {
    const u16* qb = qkv + (size_t)(tok0 + qw + qf * 16 + r) * QKVW + h * HD;
    aq[qf][0] = *(const short8*)(qb + g * 8);
    aq[qf][1] = *(const short8*)(qb + 32 + g * 8);
  }

  float l_st[2] = {0.f, 0.f};
  f32x4 oc[2][4] = {};

  const int sr = tid >> 3;
  const int sc = (tid & 7) * 8;
  const int nt = 2 * qt + 2;

  const u16* kg = qkv + (size_t)tok0 * QKVW + EMB + h * HD;
  const u16* vg = vT + (size_t)(h * HD) * NTOK + tok0;
  const int e0 = sc ^ ((sr & 7) << 3);

  auto stage = [&](int buf, int kt) {
    const size_t koff = (size_t)kt * 64;
    u16* kb = (u16*)Kb[buf] + wave * 512;
    u16* vb = (u16*)Vb[buf] + wave * 512;
    g2l16(kg + (koff + sr) * QKVW + e0, kb);
    g2l16(kg + (koff + sr + 32) * QKVW + e0, kb + 2048);
    g2l16(vg + (size_t)sr * NTOK + koff + e0, vb);
    g2l16(vg + (size_t)(sr + 32) * NTOK + koff + e0, vb + 2048);
  };

  stage(0, 0);
  for (int kb = 0; kb < nt; ++kb) {
    __syncthreads();
    const int cur = kb & 1;
    if (kb + 1 < nt) stage(cur ^ 1, kb + 1);

    const int kv0 = kb * 64;
    if (kv0 > qw + 31) continue;

    short8 kf[4][2];
#pragma unroll
    for (int nf = 0; nf < 4; ++nf) {
      const int row = nf * 16 + r;
#pragma unroll
      for (int kk = 0; kk < 2; ++kk)
        kf[nf][kk] = *(const short8*)((char*)Kb[cur] + row * 128 +
                                      ((kk * 64 + g * 16) ^ ((row & 7) << 4)));
    }
    short8 bv[2][4];
#pragma unroll
    for (int half = 0; half < 2; ++half)
#pragma unroll
      for (int nd = 0; nd < 4; ++nd) {
        const int vr = nd * 16 + r;
        bv[half][nd] = *(const short8*)((char*)Vb[cur] + vr * 128 +
                       ((half * 64 + g * 16) ^ ((vr & 7) << 4)));
      }

#pragma unroll
    for (int qf = 0; qf < 2; ++qf) {
      f32x4 st[4];
#pragma unroll
      for (int nf = 0; nf < 4; ++nf) {
        f32x4 z = {};
        z = __builtin_amdgcn_mfma_f32_16x16x32_bf16(kf[nf][0], aq[qf][0], z, 0, 0, 0);
        z = __builtin_amdgcn_mfma_f32_16x16x32_bf16(kf[nf][1], aq[qf][1], z, 0, 0, 0);
        st[nf] = z;
      }
      if (kv0 + 63 > qw + qf * 16) {
        const int qg = qw + qf * 16 + r;
#pragma unroll
        for (int nf = 0; nf < 4; ++nf)
#pragma unroll
          for (int j = 0; j < 4; ++j)
            if (kv0 + nf * 16 + 4 * g + j > qg) st[nf][j] = -3e38f;
      }
      float p[4][4];
      float ps = 0.f;
#pragma unroll
      for (int nf = 0; nf < 4; ++nf)
#pragma unroll
        for (int j = 0; j < 4; ++j) {
          const float pe = exp2f(st[nf][j] * CEXP);
          p[nf][j] = pe;
          ps += pe;
        }
      ps += __shfl_xor(ps, 16);
      ps += __shfl_xor(ps, 32);
      l_st[qf] += ps;

      u16* Pw = (u16*)Pt[wave];
#pragma unroll
      for (int nf = 0; nf < 4; ++nf) {
        uint2 w2;
        w2.x = pkbf(p[nf][0], p[nf][1]);
        w2.y = pkbf(p[nf][2], p[nf][3]);
        *(uint2*)((char*)Pw + r * 128 + ((nf * 32 + g * 8) ^ ((r & 7) << 4))) = w2;
      }
#pragma unroll
      for (int half = 0; half < 2; ++half) {
        short8 pa = *(const short8*)((char*)Pw + r * 128 +
                                     ((half * 64 + g * 16) ^ ((r & 7) << 4)));
#pragma unroll
        for (int nd = 0; nd < 4; ++nd)
          oc[qf][nd] = __builtin_amdgcn_mfma_f32_16x16x32_bf16(pa, bv[half][nd], oc[qf][nd], 0, 0, 0);
      }
    }
  }

#pragma unroll
  for (int qf = 0; qf < 2; ++qf) {
    const float rl = 1.f / l_st[qf];
#pragma unroll
    for (int j = 0; j < 4; ++j) {
      const float rj = __shfl(rl, 4 * g + j, 16);
      const size_t row = (size_t)tok0 + qw + qf * 16 + 4 * g + j;
#pragma unroll
      for (int nd = 0; nd < 4; ++nd)
        ctx[row * EMB + h * HD + nd * 16 + r] = f2bf(oc[qf][nd][j] * rj);
    }
  }
}

extern "C" void kernel_launch(void* const* d_in, const int* in_sizes, int n_in,
                              void* d_out, int out_size, void* d_ws, size_t ws_size,
                              hipStream_t stream) {
  const float* x    = (const float*)d_in[0];
  const float* Wq   = (const float*)d_in[1];
  const float* Wk   = (const float*)d_in[2];
  const float* Wv   = (const float*)d_in[3];
  const float* Wo   = (const float*)d_in[4];
  const float* bo   = (const float*)d_in[5];
  const float* W1   = (const float*)d_in[6];
  const float* b1   = (const float*)d_in[7];
  const float* W2   = (const float*)d_in[8];
  const float* b2   = (const float*)d_in[9];
  const float* ln1s = (const float*)d_in[10];
  const float* ln1b = (const float*)d_in[11];
  const float* ln2s = (const float*)d_in[12];
  const float* ln2b = (const float*)d_in[13];

  char* p = (char*)d_ws;
  u16* qkvT = (u16*)p; p += (size_t)QKVW * EMB * 2;
  u16* woT  = (u16*)p; p += (size_t)EMB * EMB * 2;
  u16* w1T  = (u16*)p; p += (size_t)FFD * EMB * 2;
  u16* w2T  = (u16*)p; p += (size_t)EMB * FFD * 2;
  u16* h1   = (u16*)p; p += (size_t)NTOK * EMB * 2;
  u16* qkv  = (u16*)p; p += (size_t)NTOK * QKVW * 2;
  u16* x2bf = (u16*)p; p += (size_t)NTOK * EMB * 2;
  u16* ff1  = (u16*)p; p += (size_t)NTOK * FFD * 2;
  u16* ctxb = h1;        // h1 dead after QKV GEMM
  u16* h2   = qkv;       // qkv dead after attention
  u16* vT   = ff1;       // vT lives [QKV GEMM, attn); ff1 lives [FF1 GEMM, end)

  if (ws_size < (size_t)(p - (char*)d_ws)) return;

  dim3 blk(256);
  prep_kernel<<<8960, blk, 0, stream>>>(Wq, Wk, Wv, Wo, W1, W2, qkvT, woT, w1T, w2T,
                                        x, ln1s, ln1b, h1);
  gemm_kernel<3, 128, false, NTOK, QKVW, EMB, 1, 18><<<dim3(18, 64), blk, 0, stream>>>(
      h1, qkvT, qkv, nullptr, nullptr, nullptr, vT);
  attn_kernel<<<dim3(96, 8), blk, 0, stream>>>(qkv, vT, ctxb);
  gemm_kernel<4, 64, true, NTOK, EMB, EMB, 1, 6><<<dim3(6, 128), blk, 0, stream>>>(
      ctxb, woT, x2bf, bo, x, nullptr, nullptr);
  ln_bf_vec_kernel<<<NTOK / 4, blk, 0, stream>>>(x2bf, ln2s, ln2b, h2);
  gemm_kernel<2, 128, true, NTOK, FFD, EMB, 4, 12><<<dim3(24, 64), blk, 0, stream>>>(
      h2, w1T, ff1, b1, nullptr, nullptr, nullptr);
  gemm_kernel<5, 64, true, NTOK, EMB, FFD, 1, 6><<<dim3(6, 128), blk, 0, stream>>>(
      ff1, w2T, (float*)d_out, b2, nullptr, x2bf, nullptr);
}

// Round 16
// 219.697 us; speedup vs baseline: 1.2752x; 1.0002x over previous
//
#include <hip/hip_runtime.h>
#include <hip/hip_bf16.h>
#include <stdint.h>
#include <stddef.h>

#define EMB 768
#define FFD 3072
#define NHEAD 12
#define HD 64
#define SEQ 1024
#define NTOK 8192
#define QKVW 2304

typedef unsigned short u16;
typedef __attribute__((ext_vector_type(8))) short short8;
typedef __attribute__((ext_vector_type(4))) float f32x4;

__device__ __forceinline__ u16 f2bf(float f) {
  union { float f; uint32_t u; } w; w.f = f;
  uint32_t x = w.u + 0x7fffu + ((w.u >> 16) & 1u);
  return (u16)(x >> 16);
}

__device__ __forceinline__ float bf2f(uint32_t v) {
  union { uint32_t u; float f; } c; c.u = v << 16; return c.f;
}

__device__ __forceinline__ uint32_t pkbf(float lo, float hi) {
  __hip_bfloat162 h = __float22bfloat162_rn(float2{lo, hi});
  union { __hip_bfloat162 h; uint32_t u; } cv; cv.h = h;
  return cv.u;
}

__device__ __forceinline__ void g2l16(const void* g, void* l) {
  __builtin_amdgcn_global_load_lds(
      (const __attribute__((address_space(1))) void*)g,
      (__attribute__((address_space(3))) void*)l, 16, 0, 0);
}

// ------------- prep kernel: 6 weight transposes + LN1, flat block decode ------
__global__ __launch_bounds__(256)
void prep_kernel(const float* __restrict__ Wq, const float* __restrict__ Wk,
                 const float* __restrict__ Wv, const float* __restrict__ Wo,
                 const float* __restrict__ W1, const float* __restrict__ W2,
                 u16* __restrict__ qkvT, u16* __restrict__ woT,
                 u16* __restrict__ w1T, u16* __restrict__ w2T,
                 const float* __restrict__ x, const float* __restrict__ sc,
                 const float* __restrict__ sh, u16* __restrict__ h1) {
  __shared__ float tile[32][33];
  const int id = blockIdx.x;
  if (id >= 6912) {
    const int wave = threadIdx.x >> 6, lane = threadIdx.x & 63;
    const int row = (id - 6912) * 4 + wave;
    const float* xr = x + (size_t)row * EMB;
    float4 v[3];
    float s = 0.f, ss = 0.f;
#pragma unroll
    for (int i = 0; i < 3; ++i) {
      v[i] = *(const float4*)(xr + lane * 4 + i * 256);
      s += v[i].x + v[i].y + v[i].z + v[i].w;
      ss += v[i].x * v[i].x + v[i].y * v[i].y + v[i].z * v[i].z + v[i].w * v[i].w;
    }
#pragma unroll
    for (int m = 1; m < 64; m <<= 1) { s += __shfl_xor(s, m, 64); ss += __shfl_xor(ss, m, 64); }
    const float mean = s * (1.f / EMB);
    const float inv = rsqrtf(ss * (1.f / EMB) - mean * mean + 1e-5f);
    u16* orow = h1 + (size_t)row * EMB;
#pragma unroll
    for (int i = 0; i < 3; ++i) {
      const int c = lane * 4 + i * 256;
      const float4 s4 = *(const float4*)(sc + c);
      const float4 h4 = *(const float4*)(sh + c);
      uint2 w2;
      w2.x = pkbf((v[i].x - mean) * inv * s4.x + h4.x, (v[i].y - mean) * inv * s4.y + h4.y);
      w2.y = pkbf((v[i].z - mean) * inv * s4.z + h4.z, (v[i].w - mean) * inv * s4.w + h4.w);
      *(uint2*)(orow + c) = w2;
    }
    return;
  }
  const float* in; u16* out; int K, N, bx, by;
  if (id < 1728) {
    const int z = id / 576, rem = id % 576;
    in = z == 0 ? Wq : (z == 1 ? Wk : Wv);
    out = qkvT + (size_t)z * EMB * EMB;
    K = EMB; N = EMB; bx = rem % 24; by = rem / 24;
  } else if (id < 2304) {
    const int rem = id - 1728;
    in = Wo; out = woT; K = EMB; N = EMB; bx = rem % 24; by = rem / 24;
  } else if (id < 4608) {
    const int rem = id - 2304;
    in = W1; out = w1T; K = EMB; N = FFD; bx = rem % 96; by = rem / 96;
  } else {
    const int rem = id - 4608;
    in = W2; out = w2T; K = FFD; N = EMB; bx = rem % 24; by = rem / 24;
  }
  const int n0 = bx * 32, k0 = by * 32;
  const int tx = threadIdx.x & 31;
  const int ty = threadIdx.x >> 5;
#pragma unroll
  for (int i = 0; i < 32; i += 8)
    tile[ty + i][tx] = in[(size_t)(k0 + ty + i) * N + n0 + tx];
  __syncthreads();
#pragma unroll
  for (int i = 0; i < 32; i += 8)
    out[(size_t)(n0 + ty + i) * K + k0 + tx] = f2bf(tile[tx][ty + i]);
}

// layernorm, wave-per-row, vectorized (bf16 in)
__global__ __launch_bounds__(256)
void ln_bf_vec_kernel(const u16* __restrict__ x, const float* __restrict__ sc,
                      const float* __restrict__ sh, u16* __restrict__ out) {
  const int wave = threadIdx.x >> 6, lane = threadIdx.x & 63;
  const int row = blockIdx.x * 4 + wave;
  const u16* xr = x + (size_t)row * EMB;
  float v[3][4];
  float s = 0.f, ss = 0.f;
#pragma unroll
  for (int i = 0; i < 3; ++i) {
    const uint2 r2 = *(const uint2*)(xr + lane * 4 + i * 256);
    v[i][0] = bf2f(r2.x & 0xffffu);
    v[i][1] = bf2f(r2.x >> 16);
    v[i][2] = bf2f(r2.y & 0xffffu);
    v[i][3] = bf2f(r2.y >> 16);
#pragma unroll
    for (int j = 0; j < 4; ++j) { s += v[i][j]; ss += v[i][j] * v[i][j]; }
  }
#pragma unroll
  for (int m = 1; m < 64; m <<= 1) { s += __shfl_xor(s, m, 64); ss += __shfl_xor(ss, m, 64); }
  const float mean = s * (1.f / EMB);
  const float inv = rsqrtf(ss * (1.f / EMB) - mean * mean + 1e-5f);
  u16* orow = out + (size_t)row * EMB;
#pragma unroll
  for (int i = 0; i < 3; ++i) {
    const int c = lane * 4 + i * 256;
    const float4 s4 = *(const float4*)(sc + c);
    const float4 h4 = *(const float4*)(sh + c);
    uint2 w2;
    w2.x = pkbf((v[i][0] - mean) * inv * s4.x + h4.x, (v[i][1] - mean) * inv * s4.y + h4.y);
    w2.y = pkbf((v[i][2] - mean) * inv * s4.z + h4.z, (v[i][3] - mean) * inv * s4.w + h4.w);
    *(uint2*)(orow + c) = w2;
  }
}

// ---------------- bf16 GEMM: C[M,N] = A[M,K] @ BT[N,K]^T ----------------
// r15 verbatim (single-buffered, 16x16x32, BK=64, conflict-free XOR swizzle,
// XCD swizzle + GM x GN super-tile decode; GM=1,GN=GX is identity).
// SWAP=true: mfma(bf, af) -> lane holds one M-row, 4 consecutive N-cols.
// EPI 2 (SWAP): C bf16 = gelu_tanh(acc + bias[n])          (uint2 st)
// EPI 4 (SWAP): C bf16 = acc + bias[n] + resf32[m*N+n]     (uint2 st)
// EPI 5 (SWAP): C f32  = acc + bias[n] + bf2f(res16[...])  (float4 st)
// EPI 3 (!SWAP): QKV split (cols<1536 row-major bf16; V cols -> vTp transposed)
template <int EPI, int MT, bool SWAP, int M, int N, int K, int GM, int GN>
__global__ __launch_bounds__(256)
void gemm_kernel(const u16* __restrict__ A, const u16* __restrict__ BT,
                 void* __restrict__ Cp, const float* __restrict__ bias,
                 const float* __restrict__ res, const u16* __restrict__ res16,
                 u16* __restrict__ vTp) {
  constexpr int MI = MT / 32;
  constexpr int GX = N / 128;
  constexpr int MB_ = M / MT;
  constexpr int NWG = GX * MB_;
  static_assert(MB_ % GM == 0 && GX % GN == 0, "group decode");
  __shared__ u16 As[MT * 64];
  __shared__ u16 Bs[128 * 64];

  const int orig = blockIdx.y * GX + blockIdx.x;
  const int swz = (orig & 7) * (NWG >> 3) + (orig >> 3);
  constexpr int SUP = GM * GN;
  constexpr int SPM = MB_ / GM;
  const int sup = swz / SUP;
  const int loc = swz % SUP;
  const int m0 = ((sup % SPM) * GM + (loc % GM)) * MT;
  const int n0 = ((sup / SPM) * GN + (loc / GM)) * 128;

  const int tid = threadIdx.x;
  const int wave = tid >> 6, lane = tid & 63;
  const int wr = wave >> 1, wc = wave & 1;
  const int r = lane & 15, g = lane >> 4;
  const int lrow = lane >> 3;
  const int lelem = (lane & 7) * 8;

  f32x4 acc[MI][4] = {};

  constexpr int NKT = K / 64;
  for (int kt = 0; kt < NKT; ++kt) {
    const int k0 = kt << 6;
    if (kt) __syncthreads();
#pragma unroll
    for (int q = 0; q < MT / 32; ++q) {
      const int chunk = q * 4 + wave;
      const int row = chunk * 8 + lrow;
      const int e = lelem ^ ((row & 7) << 3);
      g2l16(A + (size_t)(m0 + row) * K + k0 + e, As + chunk * 512);
    }
#pragma unroll
    for (int q = 0; q < 4; ++q) {
      const int chunk = q * 4 + wave;
      const int row = chunk * 8 + lrow;
      const int e = lelem ^ ((row & 7) << 3);
      g2l16(BT + (size_t)(n0 + row) * K + k0 + e, Bs + chunk * 512);
    }
    __syncthreads();
#pragma unroll
    for (int kk = 0; kk < 2; ++kk) {
      short8 af[MI], bf[4];
#pragma unroll
      for (int mi = 0; mi < MI; ++mi) {
        const int row = wr * (MT / 2) + mi * 16 + r;
        af[mi] = *(const short8*)(As + row * 64 + ((kk * 32 + g * 8) ^ ((row & 7) << 3)));
      }
#pragma unroll
      for (int ni = 0; ni < 4; ++ni) {
        const int row = wc * 64 + ni * 16 + r;
        bf[ni] = *(const short8*)(Bs + row * 64 + ((kk * 32 + g * 8) ^ ((row & 7) << 3)));
      }
#pragma unroll
      for (int mi = 0; mi < MI; ++mi)
#pragma unroll
        for (int ni = 0; ni < 4; ++ni) {
          if constexpr (SWAP)
            acc[mi][ni] = __builtin_amdgcn_mfma_f32_16x16x32_bf16(bf[ni], af[mi], acc[mi][ni], 0, 0, 0);
          else
            acc[mi][ni] = __builtin_amdgcn_mfma_f32_16x16x32_bf16(af[mi], bf[ni], acc[mi][ni], 0, 0, 0);
        }
    }
  }

  if constexpr (!SWAP) {
    // EPI 3: lane owns col = n0+wc*64+ni*16+r (fixed), rows rowb+0..3
#pragma unroll
    for (int mi = 0; mi < MI; ++mi)
#pragma unroll
      for (int ni = 0; ni < 4; ++ni) {
        const int rowb = m0 + wr * (MT / 2) + mi * 16 + 4 * g;
        const int col = n0 + wc * 64 + ni * 16 + r;
        u16 pk[4];
#pragma unroll
        for (int j = 0; j < 4; ++j) pk[j] = f2bf(acc[mi][ni][j]);
        if (col < 1536) {
#pragma unroll
          for (int j = 0; j < 4; ++j)
            ((u16*)Cp)[(size_t)(rowb + j) * N + col] = pk[j];
        } else {
          uint2 w2;
          w2.x = (uint32_t)pk[0] | ((uint32_t)pk[1] << 16);
          w2.y = (uint32_t)pk[2] | ((uint32_t)pk[3] << 16);
          *(uint2*)(vTp + (size_t)(col - 1536) * NTOK + rowb) = w2;
        }
      }
  } else {
    // SWAP epilogue: lane owns m (fixed), 4 consecutive cols nb..nb+3
#pragma unroll
    for (int mi = 0; mi < MI; ++mi) {
      const int m = m0 + wr * (MT / 2) + mi * 16 + r;
#pragma unroll
      for (int ni = 0; ni < 4; ++ni) {
        const int nb = n0 + wc * 64 + ni * 16 + 4 * g;
        if constexpr (EPI == 2) {
          const float4 bs = *(const float4*)(bias + nb);
          float tj[4];
#pragma unroll
          for (int j = 0; j < 4; ++j) {
            float t = acc[mi][ni][j] + (&bs.x)[j];
            float e = __expf(1.5957691216057308f * (t + 0.044715f * t * t * t));
            tj[j] = 0.5f * t * (1.f + (1.f - 2.f / (e + 1.f)));
          }
          uint2 w2;
          w2.x = pkbf(tj[0], tj[1]);
          w2.y = pkbf(tj[2], tj[3]);
          *(uint2*)((u16*)Cp + (size_t)m * N + nb) = w2;
        } else if constexpr (EPI == 4) {
          const float4 bs = *(const float4*)(bias + nb);
          const float4 rs = *(const float4*)(res + (size_t)m * N + nb);
          uint2 w2;
          w2.x = pkbf(acc[mi][ni][0] + bs.x + rs.x, acc[mi][ni][1] + bs.y + rs.y);
          w2.y = pkbf(acc[mi][ni][2] + bs.z + rs.z, acc[mi][ni][3] + bs.w + rs.w);
          *(uint2*)((u16*)Cp + (size_t)m * N + nb) = w2;
        } else {  // EPI 5
          const float4 bs = *(const float4*)(bias + nb);
          const uint2 r2 = *(const uint2*)(res16 + (size_t)m * N + nb);
          float4 o;
          o.x = acc[mi][ni][0] + bs.x + bf2f(r2.x & 0xffffu);
          o.y = acc[mi][ni][1] + bs.y + bf2f(r2.x >> 16);
          o.z = acc[mi][ni][2] + bs.z + bf2f(r2.y & 0xffffu);
          o.w = acc[mi][ni][3] + bs.w + bf2f(r2.y >> 16);
          *(float4*)((float*)Cp + (size_t)m * N + nb) = o;
        }
      }
    }
  }
}

// ---------------- flash attention, causal, QBLK=128, swapped-QK^T --------
// r15 + T5: s_setprio(1) around the two MFMA clusters (m191: +4-7% attn;
// NOT applied to GEMMs, where lockstep waves make it neutral/negative, m190).
#define CEXP 0.18033688011112042f  /* log2(e)/8 */

__global__ __launch_bounds__(256, 3)
void attn_kernel(const u16* __restrict__ qkv, const u16* __restrict__ vT,
                 u16* __restrict__ ctx) {
  const int bh = blockIdx.x;
  const int qt = blockIdx.y;
  const int b = bh / NHEAD, h = bh % NHEAD;
  const int tid = threadIdx.x;
  const int wave = tid >> 6, lane = tid & 63;
  const int r = lane & 15, g = lane >> 4;

  __shared__ u16 Kb[2][64 * 64];
  __shared__ u16 Vb[2][64 * 64];
  __shared__ u16 Pt[4][16 * 64];

  const int qw = qt * 128 + wave * 32;
  const int tok0 = b * SEQ;

  short8 aq[2][2];
#pragma unroll
  for (int qf = 0; qf < 2; ++qf) {
    const u16* qb = qkv + (size_t)(tok0 + qw + qf * 16 + r) * QKVW + h * HD;
    aq[qf][0] = *(const short8*)(qb + g * 8);
    aq[qf][1] = *(const short8*)(qb + 32 + g * 8);
  }

  float l_st[2] = {0.f, 0.f};
  f32x4 oc[2][4] = {};

  const int sr = tid >> 3;
  const int sc = (tid & 7) * 8;
  const int nt = 2 * qt + 2;

  const u16* kg = qkv + (size_t)tok0 * QKVW + EMB + h * HD;
  const u16* vg = vT + (size_t)(h * HD) * NTOK + tok0;
  const int e0 = sc ^ ((sr & 7) << 3);

  auto stage = [&](int buf, int kt) {
    const size_t koff = (size_t)kt * 64;
    u16* kb = (u16*)Kb[buf] + wave * 512;
    u16* vb = (u16*)Vb[buf] + wave * 512;
    g2l16(kg + (koff + sr) * QKVW + e0, kb);
    g2l16(kg + (koff + sr + 32) * QKVW + e0, kb + 2048);
    g2l16(vg + (size_t)sr * NTOK + koff + e0, vb);
    g2l16(vg + (size_t)(sr + 32) * NTOK + koff + e0, vb + 2048);
  };

  stage(0, 0);
  for (int kb = 0; kb < nt; ++kb) {
    __syncthreads();
    const int cur = kb & 1;
    if (kb + 1 < nt) stage(cur ^ 1, kb + 1);

    const int kv0 = kb * 64;
    if (kv0 > qw + 31) continue;

    short8 kf[4][2];
#pragma unroll
    for (int nf = 0; nf < 4; ++nf) {
      const int row = nf * 16 + r;
#pragma unroll
      for (int kk = 0; kk < 2; ++kk)
        kf[nf][kk] = *(const short8*)((char*)Kb[cur] + row * 128 +
                                      ((kk * 64 + g * 16) ^ ((row & 7) << 4)));
    }
    short8 bv[2][4];
#pragma unroll
    for (int half = 0; half < 2; ++half)
#pragma unroll
      for (int nd = 0; nd < 4; ++nd) {
        const int vr = nd * 16 + r;
        bv[half][nd] = *(const short8*)((char*)Vb[cur] + vr * 128 +
                       ((half * 64 + g * 16) ^ ((vr & 7) << 4)));
      }

#pragma unroll
    for (int qf = 0; qf < 2; ++qf) {
      f32x4 st[4];
      __builtin_amdgcn_s_setprio(1);
#pragma unroll
      for (int nf = 0; nf < 4; ++nf) {
        f32x4 z = {};
        z = __builtin_amdgcn_mfma_f32_16x16x32_bf16(kf[nf][0], aq[qf][0], z, 0, 0, 0);
        z = __builtin_amdgcn_mfma_f32_16x16x32_bf16(kf[nf][1], aq[qf][1], z, 0, 0, 0);
        st[nf] = z;
      }
      __builtin_amdgcn_s_setprio(0);
      if (kv0 + 63 > qw + qf * 16) {
        const int qg = qw + qf * 16 + r;
#pragma unroll
        for (int nf = 0; nf < 4; ++nf)
#pragma unroll
          for (int j = 0; j < 4; ++j)
            if (kv0 + nf * 16 + 4 * g + j > qg) st[nf][j] = -3e38f;
      }
      float p[4][4];
      float ps = 0.f;
#pragma unroll
      for (int nf = 0; nf < 4; ++nf)
#pragma unroll
        for (int j = 0; j < 4; ++j) {
          const float pe = exp2f(st[nf][j] * CEXP);
          p[nf][j] = pe;
          ps += pe;
        }
      ps += __shfl_xor(ps, 16);
      ps += __shfl_xor(ps, 32);
      l_st[qf] += ps;

      u16* Pw = (u16*)Pt[wave];
#pragma unroll
      for (int nf = 0; nf < 4; ++nf) {
        uint2 w2;
        w2.x = pkbf(p[nf][0], p[nf][1]);
        w2.y = pkbf(p[nf][2], p[nf][3]);
        *(uint2*)((char*)Pw + r * 128 + ((nf * 32 + g * 8) ^ ((r & 7) << 4))) = w2;
      }
#pragma unroll
      for (int half = 0; half < 2; ++half) {
        short8 pa = *(const short8*)((char*)Pw + r * 128 +
                                     ((half * 64 + g * 16) ^ ((r & 7) << 4)));
        __builtin_amdgcn_s_setprio(1);
#pragma unroll
        for (int nd = 0; nd < 4; ++nd)
          oc[qf][nd] = __builtin_amdgcn_mfma_f32_16x16x32_bf16(pa, bv[half][nd], oc[qf][nd], 0, 0, 0);
        __builtin_amdgcn_s_setprio(0);
      }
    }
  }

#pragma unroll
  for (int qf = 0; qf < 2; ++qf) {
    const float rl = 1.f / l_st[qf];
#pragma unroll
    for (int j = 0; j < 4; ++j) {
      const float rj = __shfl(rl, 4 * g + j, 16);
      const size_t row = (size_t)tok0 + qw + qf * 16 + 4 * g + j;
#pragma unroll
      for (int nd = 0; nd < 4; ++nd)
        ctx[row * EMB + h * HD + nd * 16 + r] = f2bf(oc[qf][nd][j] * rj);
    }
  }
}

extern "C" void kernel_launch(void* const* d_in, const int* in_sizes, int n_in,
                              void* d_out, int out_size, void* d_ws, size_t ws_size,
                              hipStream_t stream) {
  const float* x    = (const float*)d_in[0];
  const float* Wq   = (const float*)d_in[1];
  const float* Wk   = (const float*)d_in[2];
  const float* Wv   = (const float*)d_in[3];
  const float* Wo   = (const float*)d_in[4];
  const float* bo   = (const float*)d_in[5];
  const float* W1   = (const float*)d_in[6];
  const float* b1   = (const float*)d_in[7];
  const float* W2   = (const float*)d_in[8];
  const float* b2   = (const float*)d_in[9];
  const float* ln1s = (const float*)d_in[10];
  const float* ln1b = (const float*)d_in[11];
  const float* ln2s = (const float*)d_in[12];
  const float* ln2b = (const float*)d_in[13];

  char* p = (char*)d_ws;
  u16* qkvT = (u16*)p; p += (size_t)QKVW * EMB * 2;
  u16* woT  = (u16*)p; p += (size_t)EMB * EMB * 2;
  u16* w1T  = (u16*)p; p += (size_t)FFD * EMB * 2;
  u16* w2T  = (u16*)p; p += (size_t)EMB * FFD * 2;
  u16* h1   = (u16*)p; p += (size_t)NTOK * EMB * 2;
  u16* qkv  = (u16*)p; p += (size_t)NTOK * QKVW * 2;
  u16* x2bf = (u16*)p; p += (size_t)NTOK * EMB * 2;
  u16* ff1  = (u16*)p; p += (size_t)NTOK * FFD * 2;
  u16* ctxb = h1;        // h1 dead after QKV GEMM
  u16* h2   = qkv;       // qkv dead after attention
  u16* vT   = ff1;       // vT lives [QKV GEMM, attn); ff1 lives [FF1 GEMM, end)

  if (ws_size < (size_t)(p - (char*)d_ws)) return;

  dim3 blk(256);
  prep_kernel<<<8960, blk, 0, stream>>>(Wq, Wk, Wv, Wo, W1, W2, qkvT, woT, w1T, w2T,
                                        x, ln1s, ln1b, h1);
  gemm_kernel<3, 128, false, NTOK, QKVW, EMB, 1, 18><<<dim3(18, 64), blk, 0, stream>>>(
      h1, qkvT, qkv, nullptr, nullptr, nullptr, vT);
  attn_kernel<<<dim3(96, 8), blk, 0, stream>>>(qkv, vT, ctxb);
  gemm_kernel<4, 64, true, NTOK, EMB, EMB, 1, 6><<<dim3(6, 128), blk, 0, stream>>>(
      ctxb, woT, x2bf, bo, x, nullptr, nullptr);
  ln_bf_vec_kernel<<<NTOK / 4, blk, 0, stream>>>(x2bf, ln2s, ln2b, h2);
  gemm_kernel<2, 128, true, NTOK, FFD, EMB, 4, 12><<<dim3(24, 64), blk, 0, stream>>>(
      h2, w1T, ff1, b1, nullptr, nullptr, nullptr);
  gemm_kernel<5, 64, true, NTOK, EMB, FFD, 1, 6><<<dim3(6, 128), blk, 0, stream>>>(
      ff1, w2T, (float*)d_out, b2, nullptr, x2bf, nullptr);
}

// Round 17
// 214.104 us; speedup vs baseline: 1.3085x; 1.0261x over previous
//
#include <hip/hip_runtime.h>
#include <hip/hip_bf16.h>
#include <stdint.h>
#include <stddef.h>

#define EMB 768
#define FFD 3072
#define NHEAD 12
#define HD 64
#define SEQ 1024
#define NTOK 8192
#define QKVW 2304

typedef unsigned short u16;
typedef __attribute__((ext_vector_type(8))) short short8;
typedef __attribute__((ext_vector_type(4))) float f32x4;

__device__ __forceinline__ u16 f2bf(float f) {
  union { float f; uint32_t u; } w; w.f = f;
  uint32_t x = w.u + 0x7fffu + ((w.u >> 16) & 1u);
  return (u16)(x >> 16);
}

__device__ __forceinline__ float bf2f(uint32_t v) {
  union { uint32_t u; float f; } c; c.u = v << 16; return c.f;
}

__device__ __forceinline__ uint32_t pkbf(float lo, float hi) {
  __hip_bfloat162 h = __float22bfloat162_rn(float2{lo, hi});
  union { __hip_bfloat162 h; uint32_t u; } cv; cv.h = h;
  return cv.u;
}

__device__ __forceinline__ void g2l16(const void* g, void* l) {
  __builtin_amdgcn_global_load_lds(
      (const __attribute__((address_space(1))) void*)g,
      (__attribute__((address_space(3))) void*)l, 16, 0, 0);
}

// ------------- prep kernel: 6 weight transposes + LN1, flat block decode ------
__global__ __launch_bounds__(256)
void prep_kernel(const float* __restrict__ Wq, const float* __restrict__ Wk,
                 const float* __restrict__ Wv, const float* __restrict__ Wo,
                 const float* __restrict__ W1, const float* __restrict__ W2,
                 u16* __restrict__ qkvT, u16* __restrict__ woT,
                 u16* __restrict__ w1T, u16* __restrict__ w2T,
                 const float* __restrict__ x, const float* __restrict__ sc,
                 const float* __restrict__ sh, u16* __restrict__ h1) {
  __shared__ float tile[32][33];
  const int id = blockIdx.x;
  if (id >= 6912) {
    const int wave = threadIdx.x >> 6, lane = threadIdx.x & 63;
    const int row = (id - 6912) * 4 + wave;
    const float* xr = x + (size_t)row * EMB;
    float4 v[3];
    float s = 0.f, ss = 0.f;
#pragma unroll
    for (int i = 0; i < 3; ++i) {
      v[i] = *(const float4*)(xr + lane * 4 + i * 256);
      s += v[i].x + v[i].y + v[i].z + v[i].w;
      ss += v[i].x * v[i].x + v[i].y * v[i].y + v[i].z * v[i].z + v[i].w * v[i].w;
    }
#pragma unroll
    for (int m = 1; m < 64; m <<= 1) { s += __shfl_xor(s, m, 64); ss += __shfl_xor(ss, m, 64); }
    const float mean = s * (1.f / EMB);
    const float inv = rsqrtf(ss * (1.f / EMB) - mean * mean + 1e-5f);
    u16* orow = h1 + (size_t)row * EMB;
#pragma unroll
    for (int i = 0; i < 3; ++i) {
      const int c = lane * 4 + i * 256;
      const float4 s4 = *(const float4*)(sc + c);
      const float4 h4 = *(const float4*)(sh + c);
      uint2 w2;
      w2.x = pkbf((v[i].x - mean) * inv * s4.x + h4.x, (v[i].y - mean) * inv * s4.y + h4.y);
      w2.y = pkbf((v[i].z - mean) * inv * s4.z + h4.z, (v[i].w - mean) * inv * s4.w + h4.w);
      *(uint2*)(orow + c) = w2;
    }
    return;
  }
  const float* in; u16* out; int K, N, bx, by;
  if (id < 1728) {
    const int z = id / 576, rem = id % 576;
    in = z == 0 ? Wq : (z == 1 ? Wk : Wv);
    out = qkvT + (size_t)z * EMB * EMB;
    K = EMB; N = EMB; bx = rem % 24; by = rem / 24;
  } else if (id < 2304) {
    const int rem = id - 1728;
    in = Wo; out = woT; K = EMB; N = EMB; bx = rem % 24; by = rem / 24;
  } else if (id < 4608) {
    const int rem = id - 2304;
    in = W1; out = w1T; K = EMB; N = FFD; bx = rem % 96; by = rem / 96;
  } else {
    const int rem = id - 4608;
    in = W2; out = w2T; K = FFD; N = EMB; bx = rem % 24; by = rem / 24;
  }
  const int n0 = bx * 32, k0 = by * 32;
  const int tx = threadIdx.x & 31;
  const int ty = threadIdx.x >> 5;
#pragma unroll
  for (int i = 0; i < 32; i += 8)
    tile[ty + i][tx] = in[(size_t)(k0 + ty + i) * N + n0 + tx];
  __syncthreads();
#pragma unroll
  for (int i = 0; i < 32; i += 8)
    out[(size_t)(n0 + ty + i) * K + k0 + tx] = f2bf(tile[tx][ty + i]);
}

// layernorm, wave-per-row, vectorized (bf16 in)
__global__ __launch_bounds__(256)
void ln_bf_vec_kernel(const u16* __restrict__ x, const float* __restrict__ sc,
                      const float* __restrict__ sh, u16* __restrict__ out) {
  const int wave = threadIdx.x >> 6, lane = threadIdx.x & 63;
  const int row = blockIdx.x * 4 + wave;
  const u16* xr = x + (size_t)row * EMB;
  float v[3][4];
  float s = 0.f, ss = 0.f;
#pragma unroll
  for (int i = 0; i < 3; ++i) {
    const uint2 r2 = *(const uint2*)(xr + lane * 4 + i * 256);
    v[i][0] = bf2f(r2.x & 0xffffu);
    v[i][1] = bf2f(r2.x >> 16);
    v[i][2] = bf2f(r2.y & 0xffffu);
    v[i][3] = bf2f(r2.y >> 16);
#pragma unroll
    for (int j = 0; j < 4; ++j) { s += v[i][j]; ss += v[i][j] * v[i][j]; }
  }
#pragma unroll
  for (int m = 1; m < 64; m <<= 1) { s += __shfl_xor(s, m, 64); ss += __shfl_xor(ss, m, 64); }
  const float mean = s * (1.f / EMB);
  const float inv = rsqrtf(ss * (1.f / EMB) - mean * mean + 1e-5f);
  u16* orow = out + (size_t)row * EMB;
#pragma unroll
  for (int i = 0; i < 3; ++i) {
    const int c = lane * 4 + i * 256;
    const float4 s4 = *(const float4*)(sc + c);
    const float4 h4 = *(const float4*)(sh + c);
    uint2 w2;
    w2.x = pkbf((v[i][0] - mean) * inv * s4.x + h4.x, (v[i][1] - mean) * inv * s4.y + h4.y);
    w2.y = pkbf((v[i][2] - mean) * inv * s4.z + h4.z, (v[i][3] - mean) * inv * s4.w + h4.w);
    *(uint2*)(orow + c) = w2;
  }
}

// ---------------- bf16 GEMM: C[M,N] = A[M,K] @ BT[N,K]^T ----------------
// r15 verbatim (single-buffered, 16x16x32, BK=64, conflict-free XOR swizzle,
// XCD swizzle + GM x GN super-tile decode; GM=1,GN=GX is identity).
// SWAP=true: mfma(bf, af) -> lane holds one M-row, 4 consecutive N-cols.
// EPI 2 (SWAP): C bf16 = gelu_tanh(acc + bias[n])          (uint2 st)
// EPI 4 (SWAP): C bf16 = acc + bias[n] + resf32[m*N+n]     (uint2 st)
// EPI 5 (SWAP): C f32  = acc + bias[n] + bf2f(res16[...])  (float4 st)
// EPI 3 (!SWAP): QKV split (cols<1536 row-major bf16; V cols -> vTp transposed)
template <int EPI, int MT, bool SWAP, int M, int N, int K, int GM, int GN>
__global__ __launch_bounds__(256)
void gemm_kernel(const u16* __restrict__ A, const u16* __restrict__ BT,
                 void* __restrict__ Cp, const float* __restrict__ bias,
                 const float* __restrict__ res, const u16* __restrict__ res16,
                 u16* __restrict__ vTp) {
  constexpr int MI = MT / 32;
  constexpr int GX = N / 128;
  constexpr int MB_ = M / MT;
  constexpr int NWG = GX * MB_;
  static_assert(MB_ % GM == 0 && GX % GN == 0, "group decode");
  __shared__ u16 As[MT * 64];
  __shared__ u16 Bs[128 * 64];

  const int orig = blockIdx.y * GX + blockIdx.x;
  const int swz = (orig & 7) * (NWG >> 3) + (orig >> 3);
  constexpr int SUP = GM * GN;
  constexpr int SPM = MB_ / GM;
  const int sup = swz / SUP;
  const int loc = swz % SUP;
  const int m0 = ((sup % SPM) * GM + (loc % GM)) * MT;
  const int n0 = ((sup / SPM) * GN + (loc / GM)) * 128;

  const int tid = threadIdx.x;
  const int wave = tid >> 6, lane = tid & 63;
  const int wr = wave >> 1, wc = wave & 1;
  const int r = lane & 15, g = lane >> 4;
  const int lrow = lane >> 3;
  const int lelem = (lane & 7) * 8;

  f32x4 acc[MI][4] = {};

  constexpr int NKT = K / 64;
  for (int kt = 0; kt < NKT; ++kt) {
    const int k0 = kt << 6;
    if (kt) __syncthreads();
#pragma unroll
    for (int q = 0; q < MT / 32; ++q) {
      const int chunk = q * 4 + wave;
      const int row = chunk * 8 + lrow;
      const int e = lelem ^ ((row & 7) << 3);
      g2l16(A + (size_t)(m0 + row) * K + k0 + e, As + chunk * 512);
    }
#pragma unroll
    for (int q = 0; q < 4; ++q) {
      const int chunk = q * 4 + wave;
      const int row = chunk * 8 + lrow;
      const int e = lelem ^ ((row & 7) << 3);
      g2l16(BT + (size_t)(n0 + row) * K + k0 + e, Bs + chunk * 512);
    }
    __syncthreads();
#pragma unroll
    for (int kk = 0; kk < 2; ++kk) {
      short8 af[MI], bf[4];
#pragma unroll
      for (int mi = 0; mi < MI; ++mi) {
        const int row = wr * (MT / 2) + mi * 16 + r;
        af[mi] = *(const short8*)(As + row * 64 + ((kk * 32 + g * 8) ^ ((row & 7) << 3)));
      }
#pragma unroll
      for (int ni = 0; ni < 4; ++ni) {
        const int row = wc * 64 + ni * 16 + r;
        bf[ni] = *(const short8*)(Bs + row * 64 + ((kk * 32 + g * 8) ^ ((row & 7) << 3)));
      }
#pragma unroll
      for (int mi = 0; mi < MI; ++mi)
#pragma unroll
        for (int ni = 0; ni < 4; ++ni) {
          if constexpr (SWAP)
            acc[mi][ni] = __builtin_amdgcn_mfma_f32_16x16x32_bf16(bf[ni], af[mi], acc[mi][ni], 0, 0, 0);
          else
            acc[mi][ni] = __builtin_amdgcn_mfma_f32_16x16x32_bf16(af[mi], bf[ni], acc[mi][ni], 0, 0, 0);
        }
    }
  }

  if constexpr (!SWAP) {
    // EPI 3: lane owns col = n0+wc*64+ni*16+r (fixed), rows rowb+0..3
#pragma unroll
    for (int mi = 0; mi < MI; ++mi)
#pragma unroll
      for (int ni = 0; ni < 4; ++ni) {
        const int rowb = m0 + wr * (MT / 2) + mi * 16 + 4 * g;
        const int col = n0 + wc * 64 + ni * 16 + r;
        u16 pk[4];
#pragma unroll
        for (int j = 0; j < 4; ++j) pk[j] = f2bf(acc[mi][ni][j]);
        if (col < 1536) {
#pragma unroll
          for (int j = 0; j < 4; ++j)
            ((u16*)Cp)[(size_t)(rowb + j) * N + col] = pk[j];
        } else {
          uint2 w2;
          w2.x = (uint32_t)pk[0] | ((uint32_t)pk[1] << 16);
          w2.y = (uint32_t)pk[2] | ((uint32_t)pk[3] << 16);
          *(uint2*)(vTp + (size_t)(col - 1536) * NTOK + rowb) = w2;
        }
      }
  } else {
    // SWAP epilogue: lane owns m (fixed), 4 consecutive cols nb..nb+3
#pragma unroll
    for (int mi = 0; mi < MI; ++mi) {
      const int m = m0 + wr * (MT / 2) + mi * 16 + r;
#pragma unroll
      for (int ni = 0; ni < 4; ++ni) {
        const int nb = n0 + wc * 64 + ni * 16 + 4 * g;
        if constexpr (EPI == 2) {
          const float4 bs = *(const float4*)(bias + nb);
          float tj[4];
#pragma unroll
          for (int j = 0; j < 4; ++j) {
            float t = acc[mi][ni][j] + (&bs.x)[j];
            float e = __expf(1.5957691216057308f * (t + 0.044715f * t * t * t));
            tj[j] = 0.5f * t * (1.f + (1.f - 2.f / (e + 1.f)));
          }
          uint2 w2;
          w2.x = pkbf(tj[0], tj[1]);
          w2.y = pkbf(tj[2], tj[3]);
          *(uint2*)((u16*)Cp + (size_t)m * N + nb) = w2;
        } else if constexpr (EPI == 4) {
          const float4 bs = *(const float4*)(bias + nb);
          const float4 rs = *(const float4*)(res + (size_t)m * N + nb);
          uint2 w2;
          w2.x = pkbf(acc[mi][ni][0] + bs.x + rs.x, acc[mi][ni][1] + bs.y + rs.y);
          w2.y = pkbf(acc[mi][ni][2] + bs.z + rs.z, acc[mi][ni][3] + bs.w + rs.w);
          *(uint2*)((u16*)Cp + (size_t)m * N + nb) = w2;
        } else {  // EPI 5
          const float4 bs = *(const float4*)(bias + nb);
          const uint2 r2 = *(const uint2*)(res16 + (size_t)m * N + nb);
          float4 o;
          o.x = acc[mi][ni][0] + bs.x + bf2f(r2.x & 0xffffu);
          o.y = acc[mi][ni][1] + bs.y + bf2f(r2.x >> 16);
          o.z = acc[mi][ni][2] + bs.z + bf2f(r2.y & 0xffffu);
          o.w = acc[mi][ni][3] + bs.w + bf2f(r2.y >> 16);
          *(float4*)((float*)Cp + (size_t)m * N + nb) = o;
        }
      }
    }
  }
}

// ---------------- flash attention, causal, QBLK=128, swapped-QK^T --------
// Longest-job-first: qt = 7 - blockIdx.y so 16-tile blocks dispatch first and
// short blocks backfill the tail (work per block = 2*qt+2 tiles, 8x spread).
// bh->XCD affinity preserved (same-bh blocks stay 96 apart -> same XCD).
#define CEXP 0.18033688011112042f  /* log2(e)/8 */

__global__ __launch_bounds__(256, 3)
void attn_kernel(const u16* __restrict__ qkv, const u16* __restrict__ vT,
                 u16* __restrict__ ctx) {
  const int bh = blockIdx.x;
  const int qt = (int)gridDim.y - 1 - (int)blockIdx.y;  // longest-first
  const int b = bh / NHEAD, h = bh % NHEAD;
  const int tid = threadIdx.x;
  const int wave = tid >> 6, lane = tid & 63;
  const int r = lane & 15, g = lane >> 4;

  __shared__ u16 Kb[2][64 * 64];
  __shared__ u16 Vb[2][64 * 64];
  __shared__ u16 Pt[4][16 * 64];

  const int qw = qt * 128 + wave * 32;
  const int tok0 = b * SEQ;

  short8 aq[2][2];
#pragma unroll
  for (int qf = 0; qf < 2; ++qf) {
    const u16* qb = qkv + (size_t)(tok0 + qw + qf * 16 + r) * QKVW + h * HD;
    aq[qf][0] = *(const short8*)(qb + g * 8);
    aq[qf][1] = *(const short8*)(qb + 32 + g * 8);
  }

  float l_st[2] = {0.f, 0.f};
  f32x4 oc[2][4] = {};

  const int sr = tid >> 3;
  const int sc = (tid & 7) * 8;
  const int nt = 2 * qt + 2;

  const u16* kg = qkv + (size_t)tok0 * QKVW + EMB + h * HD;
  const u16* vg = vT + (size_t)(h * HD) * NTOK + tok0;
  const int e0 = sc ^ ((sr & 7) << 3);

  auto stage = [&](int buf, int kt) {
    const size_t koff = (size_t)kt * 64;
    u16* kb = (u16*)Kb[buf] + wave * 512;
    u16* vb = (u16*)Vb[buf] + wave * 512;
    g2l16(kg + (koff + sr) * QKVW + e0, kb);
    g2l16(kg + (koff + sr + 32) * QKVW + e0, kb + 2048);
    g2l16(vg + (size_t)sr * NTOK + koff + e0, vb);
    g2l16(vg + (size_t)(sr + 32) * NTOK + koff + e0, vb + 2048);
  };

  stage(0, 0);
  for (int kb = 0; kb < nt; ++kb) {
    __syncthreads();
    const int cur = kb & 1;
    if (kb + 1 < nt) stage(cur ^ 1, kb + 1);

    const int kv0 = kb * 64;
    if (kv0 > qw + 31) continue;

    short8 kf[4][2];
#pragma unroll
    for (int nf = 0; nf < 4; ++nf) {
      const int row = nf * 16 + r;
#pragma unroll
      for (int kk = 0; kk < 2; ++kk)
        kf[nf][kk] = *(const short8*)((char*)Kb[cur] + row * 128 +
                                      ((kk * 64 + g * 16) ^ ((row & 7) << 4)));
    }
    short8 bv[2][4];
#pragma unroll
    for (int half = 0; half < 2; ++half)
#pragma unroll
      for (int nd = 0; nd < 4; ++nd) {
        const int vr = nd * 16 + r;
        bv[half][nd] = *(const short8*)((char*)Vb[cur] + vr * 128 +
                       ((half * 64 + g * 16) ^ ((vr & 7) << 4)));
      }

#pragma unroll
    for (int qf = 0; qf < 2; ++qf) {
      f32x4 st[4];
      __builtin_amdgcn_s_setprio(1);
#pragma unroll
      for (int nf = 0; nf < 4; ++nf) {
        f32x4 z = {};
        z = __builtin_amdgcn_mfma_f32_16x16x32_bf16(kf[nf][0], aq[qf][0], z, 0, 0, 0);
        z = __builtin_amdgcn_mfma_f32_16x16x32_bf16(kf[nf][1], aq[qf][1], z, 0, 0, 0);
        st[nf] = z;
      }
      __builtin_amdgcn_s_setprio(0);
      if (kv0 + 63 > qw + qf * 16) {
        const int qg = qw + qf * 16 + r;
#pragma unroll
        for (int nf = 0; nf < 4; ++nf)
#pragma unroll
          for (int j = 0; j < 4; ++j)
            if (kv0 + nf * 16 + 4 * g + j > qg) st[nf][j] = -3e38f;
      }
      float p[4][4];
      float ps = 0.f;
#pragma unroll
      for (int nf = 0; nf < 4; ++nf)
#pragma unroll
        for (int j = 0; j < 4; ++j) {
          const float pe = exp2f(st[nf][j] * CEXP);
          p[nf][j] = pe;
          ps += pe;
        }
      ps += __shfl_xor(ps, 16);
      ps += __shfl_xor(ps, 32);
      l_st[qf] += ps;

      u16* Pw = (u16*)Pt[wave];
#pragma unroll
      for (int nf = 0; nf < 4; ++nf) {
        uint2 w2;
        w2.x = pkbf(p[nf][0], p[nf][1]);
        w2.y = pkbf(p[nf][2], p[nf][3]);
        *(uint2*)((char*)Pw + r * 128 + ((nf * 32 + g * 8) ^ ((r & 7) << 4))) = w2;
      }
#pragma unroll
      for (int half = 0; half < 2; ++half) {
        short8 pa = *(const short8*)((char*)Pw + r * 128 +
                                     ((half * 64 + g * 16) ^ ((r & 7) << 4)));
        __builtin_amdgcn_s_setprio(1);
#pragma unroll
        for (int nd = 0; nd < 4; ++nd)
          oc[qf][nd] = __builtin_amdgcn_mfma_f32_16x16x32_bf16(pa, bv[half][nd], oc[qf][nd], 0, 0, 0);
        __builtin_amdgcn_s_setprio(0);
      }
    }
  }

#pragma unroll
  for (int qf = 0; qf < 2; ++qf) {
    const float rl = 1.f / l_st[qf];
#pragma unroll
    for (int j = 0; j < 4; ++j) {
      const float rj = __shfl(rl, 4 * g + j, 16);
      const size_t row = (size_t)tok0 + qw + qf * 16 + 4 * g + j;
#pragma unroll
      for (int nd = 0; nd < 4; ++nd)
        ctx[row * EMB + h * HD + nd * 16 + r] = f2bf(oc[qf][nd][j] * rj);
    }
  }
}

extern "C" void kernel_launch(void* const* d_in, const int* in_sizes, int n_in,
                              void* d_out, int out_size, void* d_ws, size_t ws_size,
                              hipStream_t stream) {
  const float* x    = (const float*)d_in[0];
  const float* Wq   = (const float*)d_in[1];
  const float* Wk   = (const float*)d_in[2];
  const float* Wv   = (const float*)d_in[3];
  const float* Wo   = (const float*)d_in[4];
  const float* bo   = (const float*)d_in[5];
  const float* W1   = (const float*)d_in[6];
  const float* b1   = (const float*)d_in[7];
  const float* W2   = (const float*)d_in[8];
  const float* b2   = (const float*)d_in[9];
  const float* ln1s = (const float*)d_in[10];
  const float* ln1b = (const float*)d_in[11];
  const float* ln2s = (const float*)d_in[12];
  const float* ln2b = (const float*)d_in[13];

  char* p = (char*)d_ws;
  u16* qkvT = (u16*)p; p += (size_t)QKVW * EMB * 2;
  u16* woT  = (u16*)p; p += (size_t)EMB * EMB * 2;
  u16* w1T  = (u16*)p; p += (size_t)FFD * EMB * 2;
  u16* w2T  = (u16*)p; p += (size_t)EMB * FFD * 2;
  u16* h1   = (u16*)p; p += (size_t)NTOK * EMB * 2;
  u16* qkv  = (u16*)p; p += (size_t)NTOK * QKVW * 2;
  u16* x2bf = (u16*)p; p += (size_t)NTOK * EMB * 2;
  u16* ff1  = (u16*)p; p += (size_t)NTOK * FFD * 2;
  u16* ctxb = h1;        // h1 dead after QKV GEMM
  u16* h2   = qkv;       // qkv dead after attention
  u16* vT   = ff1;       // vT lives [QKV GEMM, attn); ff1 lives [FF1 GEMM, end)

  if (ws_size < (size_t)(p - (char*)d_ws)) return;

  dim3 blk(256);
  prep_kernel<<<8960, blk, 0, stream>>>(Wq, Wk, Wv, Wo, W1, W2, qkvT, woT, w1T, w2T,
                                        x, ln1s, ln1b, h1);
  gemm_kernel<3, 128, false, NTOK, QKVW, EMB, 1, 18><<<dim3(18, 64), blk, 0, stream>>>(
      h1, qkvT, qkv, nullptr, nullptr, nullptr, vT);
  attn_kernel<<<dim3(96, 8), blk, 0, stream>>>(qkv, vT, ctxb);
  gemm_kernel<4, 64, true, NTOK, EMB, EMB, 1, 6><<<dim3(6, 128), blk, 0, stream>>>(
      ctxb, woT, x2bf, bo, x, nullptr, nullptr);
  ln_bf_vec_kernel<<<NTOK / 4, blk, 0, stream>>>(x2bf, ln2s, ln2b, h2);
  gemm_kernel<2, 128, true, NTOK, FFD, EMB, 4, 12><<<dim3(24, 64), blk, 0, stream>>>(
      h2, w1T, ff1, b1, nullptr, nullptr, nullptr);
  gemm_kernel<5, 64, true, NTOK, EMB, FFD, 1, 6><<<dim3(6, 128), blk, 0, stream>>>(
      ff1, w2T, (float*)d_out, b2, nullptr, x2bf, nullptr);
}